// Round 1
// baseline (3998.174 us; speedup 1.0000x reference)
//
#include <hip/hip_runtime.h>
#include <math.h>

#define NL 4
#define TT 2048
#define DD 1024
#define KDIM 512
#define VDIM 1024
#define NH 4
#define DKH 128
#define DVH 256
#define CH 64
#define NCH 32
#define VOCAB 32000
#define SCALE_Q 0.08838834764831845f

__device__ __forceinline__ float dot4f(const float4& a, const float4& b) {
    return a.x*b.x + a.y*b.y + a.z*b.z + a.w*b.w;
}

// ---------------------------------------------------------------------------
// Embedding gather: h[t, :] = emb[ids[t], :]
// ---------------------------------------------------------------------------
__global__ __launch_bounds__(256) void embed_kernel(const int* __restrict__ ids,
                                                    const float* __restrict__ emb,
                                                    float* __restrict__ h) {
    int idx = blockIdx.x * 256 + threadIdx.x;      // over TT*DD/4
    int t = idx >> 8;                               // DD/4 = 256 float4 per row
    int c4 = idx & 255;
    float4 v = *(const float4*)(emb + (size_t)ids[t] * DD + c4 * 4);
    *(float4*)(h + (size_t)t * DD + c4 * 4) = v;
}

// ---------------------------------------------------------------------------
// Generic f32 GEMM: C[M,N] = A[M,K] @ B[K,N] (+bias). M%128==0, N%64==0, K%16==0
// ---------------------------------------------------------------------------
__global__ __launch_bounds__(256) void gemm_f32(const float* __restrict__ A,
                                                const float* __restrict__ B,
                                                const float* __restrict__ bias,
                                                float* __restrict__ C,
                                                int M, int N, int K) {
    __shared__ float As[16][128];   // transposed A tile
    __shared__ float Bs[16][64];
    const int tid = threadIdx.x;
    const int m0 = blockIdx.y * 128, n0 = blockIdx.x * 64;
    const int ty = tid >> 4, tx = tid & 15;   // ty:0..15 rows, tx:0..15 cols
    float acc[8][4];
#pragma unroll
    for (int i = 0; i < 8; i++)
#pragma unroll
        for (int j = 0; j < 4; j++) acc[i][j] = 0.f;

    for (int k0 = 0; k0 < K; k0 += 16) {
#pragma unroll
        for (int u = 0; u < 2; u++) {
            int id = tid * 2 + u;          // 0..511 float4 of A tile
            int m = id >> 2, kc = id & 3;
            float4 av = *(const float4*)(A + (size_t)(m0 + m) * K + k0 + kc * 4);
            As[kc * 4 + 0][m] = av.x; As[kc * 4 + 1][m] = av.y;
            As[kc * 4 + 2][m] = av.z; As[kc * 4 + 3][m] = av.w;
        }
        {
            int kk = tid >> 4, nc = tid & 15;
            *(float4*)&Bs[kk][nc * 4] =
                *(const float4*)(B + (size_t)(k0 + kk) * N + n0 + nc * 4);
        }
        __syncthreads();
#pragma unroll
        for (int kk = 0; kk < 16; kk++) {
            float a[8], b[4];
            *(float4*)&a[0] = *(float4*)&As[kk][ty * 8];
            *(float4*)&a[4] = *(float4*)&As[kk][ty * 8 + 4];
            *(float4*)&b[0] = *(float4*)&Bs[kk][tx * 4];
#pragma unroll
            for (int i = 0; i < 8; i++)
#pragma unroll
                for (int j = 0; j < 4; j++) acc[i][j] = fmaf(a[i], b[j], acc[i][j]);
        }
        __syncthreads();
    }
#pragma unroll
    for (int i = 0; i < 8; i++) {
        int m = m0 + ty * 8 + i;
        float4 o;
        o.x = acc[i][0]; o.y = acc[i][1]; o.z = acc[i][2]; o.w = acc[i][3];
        if (bias) {
            o.x += bias[n0 + tx * 4 + 0]; o.y += bias[n0 + tx * 4 + 1];
            o.z += bias[n0 + tx * 4 + 2]; o.w += bias[n0 + tx * 4 + 3];
        }
        *(float4*)(C + (size_t)m * N + n0 + tx * 4) = o;
    }
}

// ---------------------------------------------------------------------------
// Low-rank gate, stage 1: xg[t, j] = h[t, :] @ Wgk1[:, j]   (j < 16)
// ---------------------------------------------------------------------------
__global__ __launch_bounds__(256) void lowrank1_kernel(const float* __restrict__ h,
                                                       const float* __restrict__ W1,
                                                       float* __restrict__ xg) {
    int idx = blockIdx.x * 256 + threadIdx.x;   // TT*16
    int t = idx >> 4, j = idx & 15;
    const float* hr = h + (size_t)t * DD;
    float s = 0.f;
    for (int kk = 0; kk < DD; kk++) s = fmaf(hr[kk], W1[kk * 16 + j], s);
    xg[idx] = s;
}

// ---------------------------------------------------------------------------
// stage 2: gk = log_sigmoid(xg @ Wgk2 + bgk) / 16
// ---------------------------------------------------------------------------
__global__ __launch_bounds__(256) void lowrank2_kernel(const float* __restrict__ xg,
                                                       const float* __restrict__ W2,
                                                       const float* __restrict__ bg,
                                                       float* __restrict__ gk) {
    int idx = blockIdx.x * 256 + threadIdx.x;   // TT*KDIM
    int t = idx >> 9, n = idx & 511;
    const float* xr = xg + t * 16;
    float s = bg[n];
#pragma unroll
    for (int r = 0; r < 16; r++) s = fmaf(xr[r], W2[r * KDIM + n], s);
    float ls = fminf(s, 0.f) - log1pf(expf(-fabsf(s)));
    gk[idx] = ls * (1.f / 16.f);
}

// ---------------------------------------------------------------------------
// In-chunk inclusive cumsum of gk (in place), plus per-chunk last value
// ---------------------------------------------------------------------------
__global__ __launch_bounds__(256) void cumsum_kernel(float* __restrict__ gk,
                                                     float* __restrict__ Glast) {
    int idx = blockIdx.x * 256 + threadIdx.x;   // NCH*KDIM
    int c = idx >> 9, col = idx & 511;
    float acc = 0.f;
    float* p = gk + (size_t)c * CH * KDIM + col;
#pragma unroll 4
    for (int i = 0; i < CH; i++) { acc += p[i * KDIM]; p[i * KDIM] = acc; }
    Glast[idx] = acc;
}

// ---------------------------------------------------------------------------
// prep: q *= exp(G)*scale ; kh = k*exp(-G) (in place) ; kt = k*exp(Gend-G)
// ---------------------------------------------------------------------------
__global__ __launch_bounds__(256) void prep_kernel(float* __restrict__ q,
                                                   float* __restrict__ k,
                                                   float* __restrict__ kt,
                                                   const float* __restrict__ gk,
                                                   const float* __restrict__ Glast) {
    int idx = blockIdx.x * 256 + threadIdx.x;   // TT*KDIM
    int t = idx >> 9, col = idx & 511;
    int c = t >> 6;
    float G = gk[idx];
    float gl = Glast[c * KDIM + col];
    q[idx] = q[idx] * expf(G) * SCALE_Q;
    float kv = k[idx];
    k[idx] = kv * expf(-G);
    kt[idx] = kv * expf(gl - G);
}

// ---------------------------------------------------------------------------
// Per-chunk state contribution: U[c,h] = kt_chunk^T @ v_chunk  (128x256, split
// into two 128x128 halves per block).  grid = NCH*NH*2
// ---------------------------------------------------------------------------
__global__ __launch_bounds__(256) void chunkU_kernel(const float* __restrict__ kt,
                                                     const float* __restrict__ v,
                                                     float* __restrict__ U) {
    __shared__ float kts[64][128];
    __shared__ float vs[64][128];
    const int bid = blockIdx.x;
    const int vh = bid & 1, hh = (bid >> 1) & 3, c = bid >> 3;
    const int tid = threadIdx.x;
#pragma unroll
    for (int u = 0; u < 8; u++) {
        int id = u * 256 + tid;             // 0..2047 float4
        int i = id >> 5, cc = (id & 31) * 4;
        *(float4*)&kts[i][cc] = *(const float4*)(kt + (size_t)(c * CH + i) * KDIM + hh * DKH + cc);
        *(float4*)&vs[i][cc]  = *(const float4*)(v  + (size_t)(c * CH + i) * VDIM + hh * DVH + vh * 128 + cc);
    }
    __syncthreads();
    const int ty = tid >> 4, tx = tid & 15;
    float acc[8][8];
#pragma unroll
    for (int x = 0; x < 8; x++)
#pragma unroll
        for (int y = 0; y < 8; y++) acc[x][y] = 0.f;

    for (int i = 0; i < 64; i++) {
        float a[8], b[8];
        *(float4*)&a[0] = *(float4*)&kts[i][ty * 8];
        *(float4*)&a[4] = *(float4*)&kts[i][ty * 8 + 4];
        *(float4*)&b[0] = *(float4*)&vs[i][tx * 4];          // cols tx*4..+3
        *(float4*)&b[4] = *(float4*)&vs[i][64 + tx * 4];     // cols 64+tx*4..+3
#pragma unroll
        for (int x = 0; x < 8; x++)
#pragma unroll
            for (int y = 0; y < 8; y++) acc[x][y] = fmaf(a[x], b[y], acc[x][y]);
    }
    float* Up = U + (size_t)(c * NH + hh) * DKH * DVH;
#pragma unroll
    for (int x = 0; x < 8; x++) {
        float4 o0, o1;
        o0.x = acc[x][0]; o0.y = acc[x][1]; o0.z = acc[x][2]; o0.w = acc[x][3];
        o1.x = acc[x][4]; o1.y = acc[x][5]; o1.z = acc[x][6]; o1.w = acc[x][7];
        *(float4*)(Up + (size_t)(ty * 8 + x) * DVH + vh * 128 + tx * 4)      = o0;
        *(float4*)(Up + (size_t)(ty * 8 + x) * DVH + vh * 128 + 64 + tx * 4) = o1;
    }
}

// ---------------------------------------------------------------------------
// Sequential (over chunks) state recurrence, parallel over (h,dk,dv).
// In place: U[c] (contribution) -> Sb[c] (state BEFORE chunk c).
// ---------------------------------------------------------------------------
__global__ __launch_bounds__(256) void scan_states_kernel(float* __restrict__ U,
                                                          const float* __restrict__ Glast) {
    int idx = blockIdx.x * 256 + threadIdx.x;   // NH*DKH*DVH = 131072
    int hd = idx >> 8;        // h*DKH + dk  (0..511)
    int dv = idx & 255;
    float s = 0.f;
    for (int c = 0; c < NCH; c++) {
        float* p = U + (size_t)c * (NH * DKH * DVH) + (size_t)hd * DVH + dv;
        float u = *p;
        *p = s;
        s = s * expf(Glast[c * KDIM + hd]) + u;
    }
}

// ---------------------------------------------------------------------------
// Intra + inter chunk attention output.  grid = NCH*NH.
// O[t0+i, h*256+dv] = sum_{j<=i} A[i][j] * v[j] + qh[i] @ Sb
// ---------------------------------------------------------------------------
__global__ __launch_bounds__(256) void attn_kernel(const float* __restrict__ qh,
                                                   const float* __restrict__ kh,
                                                   const float* __restrict__ v,
                                                   const float* __restrict__ Sb,
                                                   float* __restrict__ ob) {
    __shared__ float qs[64][132];
    __shared__ float As[64][65];
    __shared__ float stage[2304];   // kh staging 64x36, or v/Sb staging 8x256
    const int tid = threadIdx.x;
    const int hh = blockIdx.x & 3, c = blockIdx.x >> 2;
    const int t0 = c * CH;

    // load qh chunk (64x128)
#pragma unroll
    for (int u = 0; u < 8; u++) {
        int id = u * 256 + tid;
        int i = id >> 5, cc = (id & 31) * 4;
        *(float4*)&qs[i][cc] = *(const float4*)(qh + (size_t)(t0 + i) * KDIM + hh * DKH + cc);
    }
    const int ig = tid >> 4, jg = tid & 15;
    const int i0 = ig * 4, j0 = jg * 4;

    float accA[4][4];
#pragma unroll
    for (int a = 0; a < 4; a++)
#pragma unroll
        for (int b = 0; b < 4; b++) accA[a][b] = 0.f;

    for (int ks = 0; ks < 128; ks += 32) {
#pragma unroll
        for (int u = 0; u < 2; u++) {
            int id = u * 256 + tid;     // 512 float4 of 64x32 tile
            int j = id >> 3, cc = (id & 7) * 4;
            *(float4*)&stage[j * 36 + cc] =
                *(const float4*)(kh + (size_t)(t0 + j) * KDIM + hh * DKH + ks + cc);
        }
        __syncthreads();
#pragma unroll
        for (int k4 = 0; k4 < 8; k4++) {
            float4 qv[4], kv[4];
#pragma unroll
            for (int ii = 0; ii < 4; ii++) qv[ii] = *(float4*)&qs[i0 + ii][ks + k4 * 4];
#pragma unroll
            for (int jj = 0; jj < 4; jj++) kv[jj] = *(float4*)&stage[(j0 + jj) * 36 + k4 * 4];
#pragma unroll
            for (int ii = 0; ii < 4; ii++)
#pragma unroll
                for (int jj = 0; jj < 4; jj++) accA[ii][jj] += dot4f(qv[ii], kv[jj]);
        }
        __syncthreads();
    }
    // causal mask (j <= i kept) and store A
#pragma unroll
    for (int ii = 0; ii < 4; ii++)
#pragma unroll
        for (int jj = 0; jj < 4; jj++)
            As[i0 + ii][j0 + jj] = (j0 + jj <= i0 + ii) ? accA[ii][jj] : 0.f;
    __syncthreads();

    float accO[4][16];
#pragma unroll
    for (int a = 0; a < 4; a++)
#pragma unroll
        for (int b = 0; b < 16; b++) accO[a][b] = 0.f;

    // O += A @ V   (K = 64 in 8 steps of 8 rows)
    for (int js = 0; js < 8; js++) {
#pragma unroll
        for (int u = 0; u < 2; u++) {
            int id = u * 256 + tid;     // 512 float4 of 8x256
            int r = id >> 6, cc = (id & 63) * 4;
            *(float4*)&stage[r * 256 + cc] =
                *(const float4*)(v + (size_t)(t0 + js * 8 + r) * VDIM + hh * DVH + cc);
        }
        __syncthreads();
#pragma unroll
        for (int j = 0; j < 8; j++) {
            float a[4];
#pragma unroll
            for (int ii = 0; ii < 4; ii++) a[ii] = As[i0 + ii][js * 8 + j];
            float4 vv[4];
#pragma unroll
            for (int qq = 0; qq < 4; qq++) vv[qq] = *(float4*)&stage[j * 256 + qq * 64 + jg * 4];
#pragma unroll
            for (int ii = 0; ii < 4; ii++)
#pragma unroll
                for (int qq = 0; qq < 4; qq++) {
                    accO[ii][qq * 4 + 0] = fmaf(a[ii], vv[qq].x, accO[ii][qq * 4 + 0]);
                    accO[ii][qq * 4 + 1] = fmaf(a[ii], vv[qq].y, accO[ii][qq * 4 + 1]);
                    accO[ii][qq * 4 + 2] = fmaf(a[ii], vv[qq].z, accO[ii][qq * 4 + 2]);
                    accO[ii][qq * 4 + 3] = fmaf(a[ii], vv[qq].w, accO[ii][qq * 4 + 3]);
                }
        }
        __syncthreads();
    }

    // O += qh @ Sb   (K = 128 in 16 steps of 8 rows)
    const float* Sbp = Sb + (size_t)(c * NH + hh) * DKH * DVH;
    for (int ks = 0; ks < 16; ks++) {
#pragma unroll
        for (int u = 0; u < 2; u++) {
            int id = u * 256 + tid;
            int r = id >> 6, cc = (id & 63) * 4;
            *(float4*)&stage[r * 256 + cc] =
                *(const float4*)(Sbp + (size_t)(ks * 8 + r) * DVH + cc);
        }
        __syncthreads();
#pragma unroll
        for (int kk = 0; kk < 8; kk++) {
            float a[4];
#pragma unroll
            for (int ii = 0; ii < 4; ii++) a[ii] = qs[i0 + ii][ks * 8 + kk];
            float4 vv[4];
#pragma unroll
            for (int qq = 0; qq < 4; qq++) vv[qq] = *(float4*)&stage[kk * 256 + qq * 64 + jg * 4];
#pragma unroll
            for (int ii = 0; ii < 4; ii++)
#pragma unroll
                for (int qq = 0; qq < 4; qq++) {
                    accO[ii][qq * 4 + 0] = fmaf(a[ii], vv[qq].x, accO[ii][qq * 4 + 0]);
                    accO[ii][qq * 4 + 1] = fmaf(a[ii], vv[qq].y, accO[ii][qq * 4 + 1]);
                    accO[ii][qq * 4 + 2] = fmaf(a[ii], vv[qq].z, accO[ii][qq * 4 + 2]);
                    accO[ii][qq * 4 + 3] = fmaf(a[ii], vv[qq].w, accO[ii][qq * 4 + 3]);
                }
        }
        __syncthreads();
    }

#pragma unroll
    for (int ii = 0; ii < 4; ii++)
#pragma unroll
        for (int qq = 0; qq < 4; qq++) {
            float4 o;
            o.x = accO[ii][qq * 4 + 0]; o.y = accO[ii][qq * 4 + 1];
            o.z = accO[ii][qq * 4 + 2]; o.w = accO[ii][qq * 4 + 3];
            *(float4*)(ob + (size_t)(t0 + i0 + ii) * VDIM + hh * DVH + qq * 64 + jg * 4) = o;
        }
}

// ---------------------------------------------------------------------------
// Per-(t,head) RMSNorm (over DV) * gnw, then * swish(g).  One wave per head.
// ---------------------------------------------------------------------------
__global__ __launch_bounds__(256) void rms_swish_kernel(float* __restrict__ o,
                                                        const float* __restrict__ g,
                                                        const float* __restrict__ nw) {
    int t = blockIdx.x;
    int tid = threadIdx.x;
    int wv = tid >> 6, ln = tid & 63;
    size_t base = (size_t)t * VDIM + wv * DVH + ln * 4;
    float4 x = *(const float4*)(o + base);
    float ss = x.x * x.x + x.y * x.y + x.z * x.z + x.w * x.w;
#pragma unroll
    for (int off = 32; off > 0; off >>= 1) ss += __shfl_xor(ss, off);
    float r = rsqrtf(ss * (1.f / 256.f) + 1e-5f);
    float4 gv = *(const float4*)(g + base);
    float4 nv = *(const float4*)(nw + ln * 4);
    float4 res;
    res.x = x.x * r * nv.x * (gv.x / (1.f + expf(-gv.x)));
    res.y = x.y * r * nv.y * (gv.y / (1.f + expf(-gv.y)));
    res.z = x.z * r * nv.z * (gv.z / (1.f + expf(-gv.z)));
    res.w = x.w * r * nv.w * (gv.w / (1.f + expf(-gv.w)));
    *(float4*)(o + base) = res;
}

// ---------------------------------------------------------------------------
// Final LayerNorm over D=1024 per row
// ---------------------------------------------------------------------------
__global__ __launch_bounds__(256) void ln_kernel(const float* __restrict__ h,
                                                 const float* __restrict__ w,
                                                 const float* __restrict__ b,
                                                 float* __restrict__ out) {
    int t = blockIdx.x;
    int tid = threadIdx.x;
    float4 x = *(const float4*)(h + (size_t)t * DD + tid * 4);
    float s = x.x + x.y + x.z + x.w;
    float ss = x.x * x.x + x.y * x.y + x.z * x.z + x.w * x.w;
#pragma unroll
    for (int off = 32; off > 0; off >>= 1) {
        s += __shfl_xor(s, off);
        ss += __shfl_xor(ss, off);
    }
    __shared__ float rs[4], rss[4];
    int wv = tid >> 6, ln = tid & 63;
    if (ln == 0) { rs[wv] = s; rss[wv] = ss; }
    __syncthreads();
    s = rs[0] + rs[1] + rs[2] + rs[3];
    ss = rss[0] + rss[1] + rss[2] + rss[3];
    float mu = s * (1.f / 1024.f);
    float var = ss * (1.f / 1024.f) - mu * mu;
    float r = rsqrtf(var + 1e-5f);
    float4 wv4 = *(const float4*)(w + tid * 4);
    float4 bv4 = *(const float4*)(b + tid * 4);
    float4 o;
    o.x = (x.x - mu) * r * wv4.x + bv4.x;
    o.y = (x.y - mu) * r * wv4.y + bv4.y;
    o.z = (x.z - mu) * r * wv4.z + bv4.z;
    o.w = (x.w - mu) * r * wv4.w + bv4.w;
    *(float4*)(out + (size_t)t * DD + tid * 4) = o;
}

// ---------------------------------------------------------------------------
extern "C" void kernel_launch(void* const* d_in, const int* in_sizes, int n_in,
                              void* d_out, int out_size, void* d_ws, size_t ws_size,
                              hipStream_t stream) {
    const int*   ids  = (const int*)d_in[0];
    const float* emb  = (const float*)d_in[1];
    const float* Wq   = (const float*)d_in[2];
    const float* Wk   = (const float*)d_in[3];
    const float* Wv   = (const float*)d_in[4];
    const float* Wg   = (const float*)d_in[5];
    const float* Wgk1 = (const float*)d_in[6];
    const float* Wgk2 = (const float*)d_in[7];
    const float* bgk  = (const float*)d_in[8];
    const float* gnw  = (const float*)d_in[9];
    const float* Wo   = (const float*)d_in[10];
    const float* lnw  = (const float*)d_in[11];
    const float* lnb  = (const float*)d_in[12];
    const float* Wlm  = (const float*)d_in[13];
    const float* blm  = (const float*)d_in[14];
    float* out = (float*)d_out;

    float* ws = (float*)d_ws;
    float* h  = ws; ws += (size_t)TT * DD;       // 2M
    float* q  = ws; ws += (size_t)TT * KDIM;     // 1M
    float* k  = ws; ws += (size_t)TT * KDIM;     // 1M
    float* kt = ws; ws += (size_t)TT * KDIM;     // 1M
    float* gk = ws; ws += (size_t)TT * KDIM;     // 1M
    float* v  = ws; ws += (size_t)TT * VDIM;     // 2M
    float* g  = ws; ws += (size_t)TT * VDIM;     // 2M
    float* ob = ws; ws += (size_t)TT * VDIM;     // 2M
    float* xg = ws; ws += (size_t)TT * 16;
    float* Gl = ws; ws += (size_t)NCH * KDIM;
    float* U  = ws; ws += (size_t)NCH * NH * DKH * DVH;  // 4M

    embed_kernel<<<TT, 256, 0, stream>>>(ids, emb, h);

    for (int l = 0; l < NL; l++) {
        const float* wq = Wq + (size_t)l * DD * KDIM;
        const float* wk = Wk + (size_t)l * DD * KDIM;
        const float* wv = Wv + (size_t)l * DD * VDIM;
        const float* wg = Wg + (size_t)l * DD * VDIM;
        const float* w1 = Wgk1 + (size_t)l * DD * 16;
        const float* w2 = Wgk2 + (size_t)l * 16 * KDIM;
        const float* bg = bgk + (size_t)l * KDIM;
        const float* nw = gnw + (size_t)l * DVH;
        const float* wo = Wo + (size_t)l * VDIM * DD;

        gemm_f32<<<dim3(KDIM / 64, TT / 128), 256, 0, stream>>>(h, wq, nullptr, q, TT, KDIM, DD);
        gemm_f32<<<dim3(KDIM / 64, TT / 128), 256, 0, stream>>>(h, wk, nullptr, k, TT, KDIM, DD);
        gemm_f32<<<dim3(VDIM / 64, TT / 128), 256, 0, stream>>>(h, wv, nullptr, v, TT, VDIM, DD);
        gemm_f32<<<dim3(VDIM / 64, TT / 128), 256, 0, stream>>>(h, wg, nullptr, g, TT, VDIM, DD);
        lowrank1_kernel<<<TT * 16 / 256, 256, 0, stream>>>(h, w1, xg);
        lowrank2_kernel<<<TT * KDIM / 256, 256, 0, stream>>>(xg, w2, bg, gk);
        cumsum_kernel<<<NCH * KDIM / 256, 256, 0, stream>>>(gk, Gl);
        prep_kernel<<<TT * KDIM / 256, 256, 0, stream>>>(q, k, kt, gk, Gl);
        chunkU_kernel<<<NCH * NH * 2, 256, 0, stream>>>(kt, v, U);
        scan_states_kernel<<<NH * DKH * DVH / 256, 256, 0, stream>>>(U, Gl);
        attn_kernel<<<NCH * NH, 256, 0, stream>>>(q, k, v, U, ob);
        rms_swish_kernel<<<TT, 256, 0, stream>>>(ob, g, nw);
        gemm_f32<<<dim3(DD / 64, TT / 128), 256, 0, stream>>>(ob, wo, nullptr, h, TT, DD, VDIM);
    }

    ln_kernel<<<TT, 256, 0, stream>>>(h, lnw, lnb, ob);
    gemm_f32<<<dim3(VOCAB / 64, TT / 128), 256, 0, stream>>>(ob, Wlm, blm, out, TT, VOCAB, DD);
}

// Round 2
// 1098.549 us; speedup vs baseline: 3.6395x; 3.6395x over previous
//
#include <hip/hip_runtime.h>
#include <hip/hip_bf16.h>
#include <math.h>

#define NL 4
#define TT 2048
#define DD 1024
#define KDIM 512
#define VDIM 1024
#define QSTR 3072     // fused qkvg row stride: q[0:512) k[512:1024) v[1024:2048) g[2048:3072)
#define NH 4
#define DKH 128
#define DVH 256
#define CH 64
#define NCH 32
#define VOCAB 32000
#define SCALE_Q 0.08838834764831845f

typedef short bf16x8 __attribute__((ext_vector_type(8)));
typedef float f32x4 __attribute__((ext_vector_type(4)));

__device__ __forceinline__ float dot4f(const float4& a, const float4& b) {
    return a.x*b.x + a.y*b.y + a.z*b.z + a.w*b.w;
}

__device__ __forceinline__ void gload_lds16(const void* g, void* l) {
    __builtin_amdgcn_global_load_lds((const __attribute__((address_space(1))) void*)g,
                                     (__attribute__((address_space(3))) void*)l, 16, 0, 0);
}

__device__ __forceinline__ void store_bf16x4(__hip_bfloat16* p, float a, float b, float c, float d) {
    union { __hip_bfloat16 h[4]; ushort4 v; } r;
    r.h[0] = __float2bfloat16(a); r.h[1] = __float2bfloat16(b);
    r.h[2] = __float2bfloat16(c); r.h[3] = __float2bfloat16(d);
    *(ushort4*)p = r.v;
}

// ---------------------------------------------------------------------------
// Embedding gather: h[t,:] = emb[ids[t],:] (f32 + bf16 copies)
// ---------------------------------------------------------------------------
__global__ __launch_bounds__(256) void embed_kernel(const int* __restrict__ ids,
                                                    const float* __restrict__ emb,
                                                    float* __restrict__ h,
                                                    __hip_bfloat16* __restrict__ hb) {
    int idx = blockIdx.x * 256 + threadIdx.x;      // TT*DD/4
    int t = idx >> 8, c4 = idx & 255;
    float4 v = *(const float4*)(emb + (size_t)ids[t] * DD + c4 * 4);
    *(float4*)(h + (size_t)t * DD + c4 * 4) = v;
    store_bf16x4(hb + (size_t)t * DD + c4 * 4, v.x, v.y, v.z, v.w);
}

// ---------------------------------------------------------------------------
// Transpose + convert: out[n][k] = bf16(in[k][n]).  in f32 [K][N]. grid (N/64, K/64)
// ---------------------------------------------------------------------------
__global__ __launch_bounds__(256) void tconv_kernel(const float* __restrict__ in,
                                                    __hip_bfloat16* __restrict__ out,
                                                    int K, int N) {
    __shared__ float t[64][65];
    const int n0 = blockIdx.x * 64, k0 = blockIdx.y * 64;
    const int tid = threadIdx.x;
    const int ty = tid >> 4, tx = tid & 15;
#pragma unroll
    for (int u = 0; u < 4; u++) {
        int r = ty + u * 16;
        float4 v = *(const float4*)(in + (size_t)(k0 + r) * N + n0 + tx * 4);
        t[r][tx * 4 + 0] = v.x; t[r][tx * 4 + 1] = v.y;
        t[r][tx * 4 + 2] = v.z; t[r][tx * 4 + 3] = v.w;
    }
    __syncthreads();
#pragma unroll
    for (int u = 0; u < 4; u++) {
        int nn = u * 16 + ty;
        store_bf16x4(out + (size_t)(n0 + nn) * K + k0 + tx * 4,
                     t[tx * 4 + 0][nn], t[tx * 4 + 1][nn],
                     t[tx * 4 + 2][nn], t[tx * 4 + 3][nn]);
    }
}

// ---------------------------------------------------------------------------
// bf16 MFMA GEMM: C[M,N] (f32) = A[M,K] @ Bt[N,K]^T (+bias), optional bf16 copy.
// 128x128 tile, BK=32, 256 threads = 4 waves (2x2), each wave 64x64 (4x4 frags).
// grid = (M/128, N/128).  K % 32 == 0, lda = ldb = K.
// ---------------------------------------------------------------------------
__global__ __launch_bounds__(256) void gemm_bf16(const __hip_bfloat16* __restrict__ A,
                                                 const __hip_bfloat16* __restrict__ Bt,
                                                 const float* __restrict__ bias,
                                                 float* __restrict__ C,
                                                 __hip_bfloat16* __restrict__ Cb,
                                                 int M, int N, int K) {
    __shared__ short a_lds[128 * 32];
    __shared__ short b_lds[128 * 32];
    const int tid = threadIdx.x;
    const int wv = tid >> 6, lane = tid & 63;
    const int wr = wv >> 1, wc = wv & 1;
    const int m0 = blockIdx.x * 128, n0 = blockIdx.y * 128;
    const int lr = lane & 15, lk = (lane >> 4) * 8;

    f32x4 acc[4][4];
#pragma unroll
    for (int m = 0; m < 4; m++)
#pragma unroll
        for (int n = 0; n < 4; n++) acc[m][n] = (f32x4)(0.f);

    for (int k0 = 0; k0 < K; k0 += 32) {
#pragma unroll
        for (int u = 0; u < 2; u++) {
            int c = wv * 128 + u * 64 + lane;
            int r = c >> 2, kc = (c & 3) * 8;
            gload_lds16(A + (size_t)(m0 + r) * K + k0 + kc,
                        &a_lds[(size_t)(wv * 128 + u * 64) * 8]);
            gload_lds16(Bt + (size_t)(n0 + r) * K + k0 + kc,
                        &b_lds[(size_t)(wv * 128 + u * 64) * 8]);
        }
        __syncthreads();
        bf16x8 af[4], bf[4];
#pragma unroll
        for (int m = 0; m < 4; m++)
            af[m] = *(const bf16x8*)&a_lds[(wr * 64 + m * 16 + lr) * 32 + lk];
#pragma unroll
        for (int n = 0; n < 4; n++)
            bf[n] = *(const bf16x8*)&b_lds[(wc * 64 + n * 16 + lr) * 32 + lk];
#pragma unroll
        for (int m = 0; m < 4; m++)
#pragma unroll
            for (int n = 0; n < 4; n++)
                acc[m][n] = __builtin_amdgcn_mfma_f32_16x16x32_bf16(af[m], bf[n], acc[m][n], 0, 0, 0);
        __syncthreads();
    }

    const int rbase = (lane >> 4) * 4;
#pragma unroll
    for (int n = 0; n < 4; n++) {
        int col = n0 + wc * 64 + n * 16 + lr;
        float bv = bias ? bias[col] : 0.f;
#pragma unroll
        for (int m = 0; m < 4; m++) {
            int row = m0 + wr * 64 + m * 16 + rbase;
#pragma unroll
            for (int r = 0; r < 4; r++) {
                float val = acc[m][n][r] + bv;
                C[(size_t)(row + r) * N + col] = val;
                if (Cb) Cb[(size_t)(row + r) * N + col] = __float2bfloat16(val);
            }
        }
    }
}

// ---------------------------------------------------------------------------
// Low-rank gate, stage 1: xg[t, j] = h[t, :] @ Wgk1[:, j]   (j < 16)
// ---------------------------------------------------------------------------
__global__ __launch_bounds__(256) void lowrank1_kernel(const float* __restrict__ h,
                                                       const float* __restrict__ W1,
                                                       float* __restrict__ xg) {
    int idx = blockIdx.x * 256 + threadIdx.x;   // TT*16
    int t = idx >> 4, j = idx & 15;
    const float* hr = h + (size_t)t * DD;
    float s = 0.f;
    for (int kk = 0; kk < DD; kk++) s = fmaf(hr[kk], W1[kk * 16 + j], s);
    xg[idx] = s;
}

// ---------------------------------------------------------------------------
// stage 2: gk = log_sigmoid(xg @ Wgk2 + bgk) / 16
// ---------------------------------------------------------------------------
__global__ __launch_bounds__(256) void lowrank2_kernel(const float* __restrict__ xg,
                                                       const float* __restrict__ W2,
                                                       const float* __restrict__ bg,
                                                       float* __restrict__ gk) {
    int idx = blockIdx.x * 256 + threadIdx.x;   // TT*KDIM
    int t = idx >> 9, n = idx & 511;
    const float* xr = xg + t * 16;
    float s = bg[n];
#pragma unroll
    for (int r = 0; r < 16; r++) s = fmaf(xr[r], W2[r * KDIM + n], s);
    float ls = fminf(s, 0.f) - log1pf(expf(-fabsf(s)));
    gk[idx] = ls * (1.f / 16.f);
}

// ---------------------------------------------------------------------------
// In-chunk inclusive cumsum of gk (in place), plus per-chunk last value
// ---------------------------------------------------------------------------
__global__ __launch_bounds__(256) void cumsum_kernel(float* __restrict__ gk,
                                                     float* __restrict__ Glast) {
    int idx = blockIdx.x * 256 + threadIdx.x;   // NCH*KDIM
    int c = idx >> 9, col = idx & 511;
    float acc = 0.f;
    float* p = gk + (size_t)c * CH * KDIM + col;
#pragma unroll 4
    for (int i = 0; i < CH; i++) { acc += p[i * KDIM]; p[i * KDIM] = acc; }
    Glast[idx] = acc;
}

// ---------------------------------------------------------------------------
// prep (in-place in qkvg): q *= exp(G)*scale ; k *= exp(-G)
// ---------------------------------------------------------------------------
__global__ __launch_bounds__(256) void prep_kernel(float* __restrict__ qkvg,
                                                   const float* __restrict__ gk) {
    int idx = blockIdx.x * 256 + threadIdx.x;   // TT*KDIM
    int t = idx >> 9, col = idx & 511;
    float G = gk[idx];
    float* qp = qkvg + (size_t)t * QSTR + col;
    qp[0]   *= expf(G) * SCALE_Q;
    qp[512] *= expf(-G);
}

// ---------------------------------------------------------------------------
// Per-chunk state contribution: U[c,h] = (kh*exp(Gl))^T @ v  (128x256 per c,h;
// two 128x128 halves per block).  grid = NCH*NH*2
// ---------------------------------------------------------------------------
__global__ __launch_bounds__(256) void chunkU_kernel(const float* __restrict__ qkvg,
                                                     const float* __restrict__ Gl,
                                                     float* __restrict__ U) {
    __shared__ float kts[64][128];
    __shared__ float vs[64][128];
    const int bid = blockIdx.x;
    const int vh = bid & 1, hh = (bid >> 1) & 3, c = bid >> 3;
    const int tid = threadIdx.x;
#pragma unroll
    for (int u = 0; u < 8; u++) {
        int id = u * 256 + tid;             // 0..2047 float4
        int i = id >> 5, cc = (id & 31) * 4;
        float4 kv = *(const float4*)(qkvg + (size_t)(c * CH + i) * QSTR + 512 + hh * DKH + cc);
        float4 gl = *(const float4*)(Gl + c * KDIM + hh * DKH + cc);
        kv.x *= expf(gl.x); kv.y *= expf(gl.y); kv.z *= expf(gl.z); kv.w *= expf(gl.w);
        *(float4*)&kts[i][cc] = kv;
        *(float4*)&vs[i][cc]  = *(const float4*)(qkvg + (size_t)(c * CH + i) * QSTR + 1024 + hh * DVH + vh * 128 + cc);
    }
    __syncthreads();
    const int ty = tid >> 4, tx = tid & 15;
    float acc[8][8];
#pragma unroll
    for (int x = 0; x < 8; x++)
#pragma unroll
        for (int y = 0; y < 8; y++) acc[x][y] = 0.f;

    for (int i = 0; i < 64; i++) {
        float a[8], b[8];
        *(float4*)&a[0] = *(float4*)&kts[i][ty * 8];
        *(float4*)&a[4] = *(float4*)&kts[i][ty * 8 + 4];
        *(float4*)&b[0] = *(float4*)&vs[i][tx * 4];
        *(float4*)&b[4] = *(float4*)&vs[i][64 + tx * 4];
#pragma unroll
        for (int x = 0; x < 8; x++)
#pragma unroll
            for (int y = 0; y < 8; y++) acc[x][y] = fmaf(a[x], b[y], acc[x][y]);
    }
    float* Up = U + (size_t)(c * NH + hh) * DKH * DVH;
#pragma unroll
    for (int x = 0; x < 8; x++) {
        float4 o0, o1;
        o0.x = acc[x][0]; o0.y = acc[x][1]; o0.z = acc[x][2]; o0.w = acc[x][3];
        o1.x = acc[x][4]; o1.y = acc[x][5]; o1.z = acc[x][6]; o1.w = acc[x][7];
        *(float4*)(Up + (size_t)(ty * 8 + x) * DVH + vh * 128 + tx * 4)      = o0;
        *(float4*)(Up + (size_t)(ty * 8 + x) * DVH + vh * 128 + 64 + tx * 4) = o1;
    }
}

// ---------------------------------------------------------------------------
// Sequential (over chunks) state recurrence, parallel over (h,dk,dv).
// In place: U[c] (contribution) -> Sb[c] (state BEFORE chunk c).
// ---------------------------------------------------------------------------
__global__ __launch_bounds__(256) void scan_states_kernel(float* __restrict__ U,
                                                          const float* __restrict__ Glast) {
    int idx = blockIdx.x * 256 + threadIdx.x;   // NH*DKH*DVH = 131072
    int hd = idx >> 8;        // h*DKH + dk
    int dv = idx & 255;
    float s = 0.f;
    for (int c = 0; c < NCH; c++) {
        float* p = U + (size_t)c * (NH * DKH * DVH) + (size_t)hd * DVH + dv;
        float u = *p;
        *p = s;
        s = s * expf(Glast[c * KDIM + hd]) + u;
    }
}

// ---------------------------------------------------------------------------
// Intra + inter chunk attention output.  grid = NCH*NH.
// ---------------------------------------------------------------------------
__global__ __launch_bounds__(256) void attn_kernel(const float* __restrict__ qkvg,
                                                   const float* __restrict__ Sb,
                                                   float* __restrict__ ob) {
    __shared__ float qs[64][132];
    __shared__ float As[64][65];
    __shared__ float stage[2304];
    const int tid = threadIdx.x;
    const int hh = blockIdx.x & 3, c = blockIdx.x >> 2;
    const int t0 = c * CH;

#pragma unroll
    for (int u = 0; u < 8; u++) {
        int id = u * 256 + tid;
        int i = id >> 5, cc = (id & 31) * 4;
        *(float4*)&qs[i][cc] = *(const float4*)(qkvg + (size_t)(t0 + i) * QSTR + hh * DKH + cc);
    }
    const int ig = tid >> 4, jg = tid & 15;
    const int i0 = ig * 4, j0 = jg * 4;

    float accA[4][4];
#pragma unroll
    for (int a = 0; a < 4; a++)
#pragma unroll
        for (int b = 0; b < 4; b++) accA[a][b] = 0.f;

    for (int ks = 0; ks < 128; ks += 32) {
#pragma unroll
        for (int u = 0; u < 2; u++) {
            int id = u * 256 + tid;
            int j = id >> 3, cc = (id & 7) * 4;
            *(float4*)&stage[j * 36 + cc] =
                *(const float4*)(qkvg + (size_t)(t0 + j) * QSTR + 512 + hh * DKH + ks + cc);
        }
        __syncthreads();
#pragma unroll
        for (int k4 = 0; k4 < 8; k4++) {
            float4 qv[4], kv[4];
#pragma unroll
            for (int ii = 0; ii < 4; ii++) qv[ii] = *(float4*)&qs[i0 + ii][ks + k4 * 4];
#pragma unroll
            for (int jj = 0; jj < 4; jj++) kv[jj] = *(float4*)&stage[(j0 + jj) * 36 + k4 * 4];
#pragma unroll
            for (int ii = 0; ii < 4; ii++)
#pragma unroll
                for (int jj = 0; jj < 4; jj++) accA[ii][jj] += dot4f(qv[ii], kv[jj]);
        }
        __syncthreads();
    }
#pragma unroll
    for (int ii = 0; ii < 4; ii++)
#pragma unroll
        for (int jj = 0; jj < 4; jj++)
            As[i0 + ii][j0 + jj] = (j0 + jj <= i0 + ii) ? accA[ii][jj] : 0.f;
    __syncthreads();

    float accO[4][16];
#pragma unroll
    for (int a = 0; a < 4; a++)
#pragma unroll
        for (int b = 0; b < 16; b++) accO[a][b] = 0.f;

    for (int js = 0; js < 8; js++) {
#pragma unroll
        for (int u = 0; u < 2; u++) {
            int id = u * 256 + tid;
            int r = id >> 6, cc = (id & 63) * 4;
            *(float4*)&stage[r * 256 + cc] =
                *(const float4*)(qkvg + (size_t)(t0 + js * 8 + r) * QSTR + 1024 + hh * DVH + cc);
        }
        __syncthreads();
#pragma unroll
        for (int j = 0; j < 8; j++) {
            float a[4];
#pragma unroll
            for (int ii = 0; ii < 4; ii++) a[ii] = As[i0 + ii][js * 8 + j];
            float4 vv[4];
#pragma unroll
            for (int qq = 0; qq < 4; qq++) vv[qq] = *(float4*)&stage[j * 256 + qq * 64 + jg * 4];
#pragma unroll
            for (int ii = 0; ii < 4; ii++)
#pragma unroll
                for (int qq = 0; qq < 4; qq++) {
                    accO[ii][qq * 4 + 0] = fmaf(a[ii], vv[qq].x, accO[ii][qq * 4 + 0]);
                    accO[ii][qq * 4 + 1] = fmaf(a[ii], vv[qq].y, accO[ii][qq * 4 + 1]);
                    accO[ii][qq * 4 + 2] = fmaf(a[ii], vv[qq].z, accO[ii][qq * 4 + 2]);
                    accO[ii][qq * 4 + 3] = fmaf(a[ii], vv[qq].w, accO[ii][qq * 4 + 3]);
                }
        }
        __syncthreads();
    }

    const float* Sbp = Sb + (size_t)(c * NH + hh) * DKH * DVH;
    for (int ks = 0; ks < 16; ks++) {
#pragma unroll
        for (int u = 0; u < 2; u++) {
            int id = u * 256 + tid;
            int r = id >> 6, cc = (id & 63) * 4;
            *(float4*)&stage[r * 256 + cc] =
                *(const float4*)(Sbp + (size_t)(ks * 8 + r) * DVH + cc);
        }
        __syncthreads();
#pragma unroll
        for (int kk = 0; kk < 8; kk++) {
            float a[4];
#pragma unroll
            for (int ii = 0; ii < 4; ii++) a[ii] = qs[i0 + ii][ks * 8 + kk];
            float4 vv[4];
#pragma unroll
            for (int qq = 0; qq < 4; qq++) vv[qq] = *(float4*)&stage[kk * 256 + qq * 64 + jg * 4];
#pragma unroll
            for (int ii = 0; ii < 4; ii++)
#pragma unroll
                for (int qq = 0; qq < 4; qq++) {
                    accO[ii][qq * 4 + 0] = fmaf(a[ii], vv[qq].x, accO[ii][qq * 4 + 0]);
                    accO[ii][qq * 4 + 1] = fmaf(a[ii], vv[qq].y, accO[ii][qq * 4 + 1]);
                    accO[ii][qq * 4 + 2] = fmaf(a[ii], vv[qq].z, accO[ii][qq * 4 + 2]);
                    accO[ii][qq * 4 + 3] = fmaf(a[ii], vv[qq].w, accO[ii][qq * 4 + 3]);
                }
        }
        __syncthreads();
    }

#pragma unroll
    for (int ii = 0; ii < 4; ii++)
#pragma unroll
        for (int qq = 0; qq < 4; qq++) {
            float4 o;
            o.x = accO[ii][qq * 4 + 0]; o.y = accO[ii][qq * 4 + 1];
            o.z = accO[ii][qq * 4 + 2]; o.w = accO[ii][qq * 4 + 3];
            *(float4*)(ob + (size_t)(t0 + i0 + ii) * VDIM + hh * DVH + qq * 64 + jg * 4) = o;
        }
}

// ---------------------------------------------------------------------------
// Per-(t,head) RMSNorm * gnw * swish(g) -> bf16
// ---------------------------------------------------------------------------
__global__ __launch_bounds__(256) void rms_swish_kernel(const float* __restrict__ o,
                                                        const float* __restrict__ qkvg,
                                                        const float* __restrict__ nw,
                                                        __hip_bfloat16* __restrict__ ob16) {
    int t = blockIdx.x;
    int tid = threadIdx.x;
    int wv = tid >> 6, ln = tid & 63;
    size_t base = (size_t)t * VDIM + wv * DVH + ln * 4;
    float4 x = *(const float4*)(o + base);
    float ss = x.x * x.x + x.y * x.y + x.z * x.z + x.w * x.w;
#pragma unroll
    for (int off = 32; off > 0; off >>= 1) ss += __shfl_xor(ss, off);
    float r = rsqrtf(ss * (1.f / 256.f) + 1e-5f);
    float4 gv = *(const float4*)(qkvg + (size_t)t * QSTR + 2048 + wv * DVH + ln * 4);
    float4 nv = *(const float4*)(nw + ln * 4);
    float a = x.x * r * nv.x * (gv.x / (1.f + expf(-gv.x)));
    float b = x.y * r * nv.y * (gv.y / (1.f + expf(-gv.y)));
    float c = x.z * r * nv.z * (gv.z / (1.f + expf(-gv.z)));
    float d = x.w * r * nv.w * (gv.w / (1.f + expf(-gv.w)));
    store_bf16x4(ob16 + base, a, b, c, d);
}

// ---------------------------------------------------------------------------
// Final LayerNorm over D=1024 per row -> bf16
// ---------------------------------------------------------------------------
__global__ __launch_bounds__(256) void ln_kernel(const float* __restrict__ h,
                                                 const float* __restrict__ w,
                                                 const float* __restrict__ b,
                                                 __hip_bfloat16* __restrict__ out16) {
    int t = blockIdx.x;
    int tid = threadIdx.x;
    float4 x = *(const float4*)(h + (size_t)t * DD + tid * 4);
    float s = x.x + x.y + x.z + x.w;
    float ss = x.x * x.x + x.y * x.y + x.z * x.z + x.w * x.w;
#pragma unroll
    for (int off = 32; off > 0; off >>= 1) {
        s += __shfl_xor(s, off);
        ss += __shfl_xor(ss, off);
    }
    __shared__ float rs[4], rss[4];
    int wv = tid >> 6;
    if ((tid & 63) == 0) { rs[wv] = s; rss[wv] = ss; }
    __syncthreads();
    s = rs[0] + rs[1] + rs[2] + rs[3];
    ss = rss[0] + rss[1] + rss[2] + rss[3];
    float mu = s * (1.f / 1024.f);
    float var = ss * (1.f / 1024.f) - mu * mu;
    float r = rsqrtf(var + 1e-5f);
    float4 wv4 = *(const float4*)(w + tid * 4);
    float4 bv4 = *(const float4*)(b + tid * 4);
    store_bf16x4(out16 + (size_t)t * DD + tid * 4,
                 (x.x - mu) * r * wv4.x + bv4.x,
                 (x.y - mu) * r * wv4.y + bv4.y,
                 (x.z - mu) * r * wv4.z + bv4.z,
                 (x.w - mu) * r * wv4.w + bv4.w);
}

// ---------------------------------------------------------------------------
extern "C" void kernel_launch(void* const* d_in, const int* in_sizes, int n_in,
                              void* d_out, int out_size, void* d_ws, size_t ws_size,
                              hipStream_t stream) {
    const int*   ids  = (const int*)d_in[0];
    const float* emb  = (const float*)d_in[1];
    const float* Wq   = (const float*)d_in[2];
    const float* Wk   = (const float*)d_in[3];
    const float* Wv   = (const float*)d_in[4];
    const float* Wg   = (const float*)d_in[5];
    const float* Wgk1 = (const float*)d_in[6];
    const float* Wgk2 = (const float*)d_in[7];
    const float* bgk  = (const float*)d_in[8];
    const float* gnw  = (const float*)d_in[9];
    const float* Wo   = (const float*)d_in[10];
    const float* lnw  = (const float*)d_in[11];
    const float* lnb  = (const float*)d_in[12];
    const float* Wlm  = (const float*)d_in[13];
    const float* blm  = (const float*)d_in[14];
    float* out = (float*)d_out;

    float* ws = (float*)d_ws;
    float* h    = ws; ws += (size_t)TT * DD;        // 2M
    float* qkvg = ws; ws += (size_t)TT * QSTR;      // 6.29M
    float* gk   = ws; ws += (size_t)TT * KDIM;      // 1M
    float* ob   = ws; ws += (size_t)TT * VDIM;      // 2M
    float* xg   = ws; ws += (size_t)TT * 16;
    float* Gl   = ws; ws += (size_t)NCH * KDIM;
    float* U    = ws; ws += (size_t)NCH * NH * DKH * DVH;  // 4M
    __hip_bfloat16* hb    = (__hip_bfloat16*)ws; ws += (size_t)TT * DD / 2;
    __hip_bfloat16* obb   = (__hip_bfloat16*)ws; ws += (size_t)TT * DD / 2;
    __hip_bfloat16* lnb16 = (__hip_bfloat16*)ws; ws += (size_t)TT * DD / 2;
    __hip_bfloat16* Wt    = (__hip_bfloat16*)ws; ws += (size_t)QSTR * DD / 2;
    __hip_bfloat16* WoT   = (__hip_bfloat16*)ws; ws += (size_t)VDIM * DD / 2;
    __hip_bfloat16* WlmT  = (__hip_bfloat16*)ws; ws += (size_t)VOCAB * DD / 2;

    embed_kernel<<<TT, 256, 0, stream>>>(ids, emb, h, hb);
    tconv_kernel<<<dim3(VOCAB / 64, DD / 64), 256, 0, stream>>>(Wlm, WlmT, DD, VOCAB);

    for (int l = 0; l < NL; l++) {
        const float* w1 = Wgk1 + (size_t)l * DD * 16;
        const float* w2 = Wgk2 + (size_t)l * 16 * KDIM;
        const float* bg = bgk + (size_t)l * KDIM;
        const float* nw = gnw + (size_t)l * DVH;

        tconv_kernel<<<dim3(KDIM / 64, DD / 64), 256, 0, stream>>>(Wq + (size_t)l * DD * KDIM, Wt,                     DD, KDIM);
        tconv_kernel<<<dim3(KDIM / 64, DD / 64), 256, 0, stream>>>(Wk + (size_t)l * DD * KDIM, Wt + (size_t)512 * DD,  DD, KDIM);
        tconv_kernel<<<dim3(VDIM / 64, DD / 64), 256, 0, stream>>>(Wv + (size_t)l * DD * VDIM, Wt + (size_t)1024 * DD, DD, VDIM);
        tconv_kernel<<<dim3(VDIM / 64, DD / 64), 256, 0, stream>>>(Wg + (size_t)l * DD * VDIM, Wt + (size_t)2048 * DD, DD, VDIM);
        tconv_kernel<<<dim3(DD / 64, VDIM / 64), 256, 0, stream>>>(Wo + (size_t)l * VDIM * DD, WoT,                    VDIM, DD);

        gemm_bf16<<<dim3(TT / 128, QSTR / 128), 256, 0, stream>>>(hb, Wt, nullptr, qkvg, nullptr, TT, QSTR, DD);
        lowrank1_kernel<<<TT * 16 / 256, 256, 0, stream>>>(h, w1, xg);
        lowrank2_kernel<<<TT * KDIM / 256, 256, 0, stream>>>(xg, w2, bg, gk);
        cumsum_kernel<<<NCH * KDIM / 256, 256, 0, stream>>>(gk, Gl);
        prep_kernel<<<TT * KDIM / 256, 256, 0, stream>>>(qkvg, gk);
        chunkU_kernel<<<NCH * NH * 2, 256, 0, stream>>>(qkvg, Gl, U);
        scan_states_kernel<<<NH * DKH * DVH / 256, 256, 0, stream>>>(U, Gl);
        attn_kernel<<<NCH * NH, 256, 0, stream>>>(qkvg, U, ob);
        rms_swish_kernel<<<TT, 256, 0, stream>>>(ob, qkvg, nw, obb);
        gemm_bf16<<<dim3(TT / 128, DD / 128), 256, 0, stream>>>(obb, WoT, nullptr, h, hb, TT, DD, VDIM);
    }

    ln_kernel<<<TT, 256, 0, stream>>>(h, lnw, lnb, lnb16);
    gemm_bf16<<<dim3(TT / 128, VOCAB / 128), 256, 0, stream>>>(lnb16, WlmT, blm, out, nullptr, TT, VOCAB, DD);
}

// Round 3
// 967.613 us; speedup vs baseline: 4.1320x; 1.1353x over previous
//
#include <hip/hip_runtime.h>
#include <hip/hip_bf16.h>
#include <math.h>

#define NL 4
#define TT 2048
#define DD 1024
#define KDIM 512
#define VDIM 1024
#define QSTR 3072     // fused qkvg row stride: q[0:512) k[512:1024) v[1024:2048) g[2048:3072)
#define NH 4
#define DKH 128
#define DVH 256
#define CH 64
#define NCH 32
#define VOCAB 32000
#define SCALE_Q 0.08838834764831845f

typedef short bf16x8 __attribute__((ext_vector_type(8)));
typedef float f32x4 __attribute__((ext_vector_type(4)));

__device__ __forceinline__ void gload_lds16(const void* g, void* l) {
    __builtin_amdgcn_global_load_lds((const __attribute__((address_space(1))) void*)g,
                                     (__attribute__((address_space(3))) void*)l, 16, 0, 0);
}

__device__ __forceinline__ void store_bf16x4(__hip_bfloat16* p, float a, float b, float c, float d) {
    union { __hip_bfloat16 h[4]; ushort4 v; } r;
    r.h[0] = __float2bfloat16(a); r.h[1] = __float2bfloat16(b);
    r.h[2] = __float2bfloat16(c); r.h[3] = __float2bfloat16(d);
    *(ushort4*)p = r.v;
}

// ---------------------------------------------------------------------------
// Embedding gather: h[t,:] = emb[ids[t],:] (f32 + bf16 copies)
// ---------------------------------------------------------------------------
__global__ __launch_bounds__(256) void embed_kernel(const int* __restrict__ ids,
                                                    const float* __restrict__ emb,
                                                    float* __restrict__ h,
                                                    __hip_bfloat16* __restrict__ hb) {
    int idx = blockIdx.x * 256 + threadIdx.x;      // TT*DD/4
    int t = idx >> 8, c4 = idx & 255;
    float4 v = *(const float4*)(emb + (size_t)ids[t] * DD + c4 * 4);
    *(float4*)(h + (size_t)t * DD + c4 * 4) = v;
    store_bf16x4(hb + (size_t)t * DD + c4 * 4, v.x, v.y, v.z, v.w);
}

// ---------------------------------------------------------------------------
// Transpose + convert: out[n][k] = bf16(in[k][n]).  in f32 [K][N]. grid (N/64, K/64)
// ---------------------------------------------------------------------------
__global__ __launch_bounds__(256) void tconv_kernel(const float* __restrict__ in,
                                                    __hip_bfloat16* __restrict__ out,
                                                    int K, int N) {
    __shared__ float tle[64][65];
    const int n0 = blockIdx.x * 64, k0 = blockIdx.y * 64;
    const int tid = threadIdx.x;
    const int ty = tid >> 4, tx = tid & 15;
#pragma unroll
    for (int u = 0; u < 4; u++) {
        int r = ty + u * 16;
        float4 v = *(const float4*)(in + (size_t)(k0 + r) * N + n0 + tx * 4);
        tle[r][tx * 4 + 0] = v.x; tle[r][tx * 4 + 1] = v.y;
        tle[r][tx * 4 + 2] = v.z; tle[r][tx * 4 + 3] = v.w;
    }
    __syncthreads();
#pragma unroll
    for (int u = 0; u < 4; u++) {
        int nn = u * 16 + ty;
        store_bf16x4(out + (size_t)(n0 + nn) * K + k0 + tx * 4,
                     tle[tx * 4 + 0][nn], tle[tx * 4 + 1][nn],
                     tle[tx * 4 + 2][nn], tle[tx * 4 + 3][nn]);
    }
}

// ---------------------------------------------------------------------------
// Per-layer weight transposes fused into one launch (1024 blocks).
// ---------------------------------------------------------------------------
__global__ __launch_bounds__(256) void tconv_layer_kernel(const float* __restrict__ wq,
                                                          const float* __restrict__ wk,
                                                          const float* __restrict__ wv,
                                                          const float* __restrict__ wg,
                                                          const float* __restrict__ wo,
                                                          __hip_bfloat16* __restrict__ Wt,
                                                          __hip_bfloat16* __restrict__ WoT) {
    __shared__ float tle[64][65];
    int b = blockIdx.x;
    const float* src; __hip_bfloat16* dst; int N, local;
    if (b < 128)      { src = wq; dst = Wt;                         N = 512;  local = b; }
    else if (b < 256) { src = wk; dst = Wt + (size_t)512 * 1024;    N = 512;  local = b - 128; }
    else if (b < 512) { src = wv; dst = Wt + (size_t)1024 * 1024;   N = 1024; local = b - 256; }
    else if (b < 768) { src = wg; dst = Wt + (size_t)2048 * 1024;   N = 1024; local = b - 512; }
    else              { src = wo; dst = WoT;                        N = 1024; local = b - 768; }
    int nbx = N >> 6;
    int n0 = (local % nbx) * 64, k0 = (local / nbx) * 64;
    const int tid = threadIdx.x;
    const int ty = tid >> 4, tx = tid & 15;
#pragma unroll
    for (int u = 0; u < 4; u++) {
        int r = ty + u * 16;
        float4 v = *(const float4*)(src + (size_t)(k0 + r) * N + n0 + tx * 4);
        tle[r][tx * 4 + 0] = v.x; tle[r][tx * 4 + 1] = v.y;
        tle[r][tx * 4 + 2] = v.z; tle[r][tx * 4 + 3] = v.w;
    }
    __syncthreads();
#pragma unroll
    for (int u = 0; u < 4; u++) {
        int nn = u * 16 + ty;
        store_bf16x4(dst + (size_t)(n0 + nn) * 1024 + k0 + tx * 4,
                     tle[tx * 4 + 0][nn], tle[tx * 4 + 1][nn],
                     tle[tx * 4 + 2][nn], tle[tx * 4 + 3][nn]);
    }
}

// ---------------------------------------------------------------------------
// bf16 MFMA GEMM, double-buffered 2-phase: C[M,N](f32) = A[M,K] @ Bt[N,K]^T (+bias).
// 128x128 tile, BK=32, 4 waves. XCD-swizzled grid (requires nwg % 8 == 0).
// ---------------------------------------------------------------------------
__global__ __launch_bounds__(256) void gemm_bf16_db(const __hip_bfloat16* __restrict__ A,
                                                    const __hip_bfloat16* __restrict__ Bt,
                                                    const float* __restrict__ bias,
                                                    float* __restrict__ C,
                                                    __hip_bfloat16* __restrict__ Cb,
                                                    int M, int N, int K) {
    __shared__ short a_lds[2][128 * 32];
    __shared__ short b_lds[2][128 * 32];
    const int tid = threadIdx.x;
    const int wv = tid >> 6, lane = tid & 63;
    const int wr = wv >> 1, wc = wv & 1;
    // bijective XCD swizzle
    const int nbx = gridDim.x;
    int wg = blockIdx.y * nbx + blockIdx.x;
    int cpx = (nbx * gridDim.y) >> 3;
    int swz = (wg & 7) * cpx + (wg >> 3);
    const int m0 = (swz % nbx) * 128, n0 = (swz / nbx) * 128;
    const int lr = lane & 15, lk = (lane >> 4) * 8;

    f32x4 acc[4][4];
#pragma unroll
    for (int m = 0; m < 4; m++)
#pragma unroll
        for (int n = 0; n < 4; n++) acc[m][n] = (f32x4)(0.f);

    auto STAGE = [&](int buf, int k0) {
#pragma unroll
        for (int u = 0; u < 2; u++) {
            int c = wv * 128 + u * 64 + lane;
            int r = c >> 2, kc = (c & 3) * 8;
            gload_lds16(A + (size_t)(m0 + r) * K + k0 + kc,
                        &a_lds[buf][(wv * 128 + u * 64) * 8]);
            gload_lds16(Bt + (size_t)(n0 + r) * K + k0 + kc,
                        &b_lds[buf][(wv * 128 + u * 64) * 8]);
        }
    };
    auto COMPUTE = [&](int buf) {
        bf16x8 af[4], bfr[4];
#pragma unroll
        for (int m = 0; m < 4; m++)
            af[m] = *(const bf16x8*)&a_lds[buf][(wr * 64 + m * 16 + lr) * 32 + lk];
#pragma unroll
        for (int n = 0; n < 4; n++)
            bfr[n] = *(const bf16x8*)&b_lds[buf][(wc * 64 + n * 16 + lr) * 32 + lk];
#pragma unroll
        for (int m = 0; m < 4; m++)
#pragma unroll
            for (int n = 0; n < 4; n++)
                acc[m][n] = __builtin_amdgcn_mfma_f32_16x16x32_bf16(af[m], bfr[n], acc[m][n], 0, 0, 0);
    };

    STAGE(0, 0);
    __syncthreads();              // compiler drains vmcnt before barrier
    int cur = 0;
    for (int k0 = 32; k0 < K; k0 += 32) {
        STAGE(cur ^ 1, k0);       // loads fly while we compute
        COMPUTE(cur);
        __syncthreads();          // drain: next buffer ready, cur fully read
        cur ^= 1;
    }
    COMPUTE(cur);

    const int rbase = (lane >> 4) * 4;
#pragma unroll
    for (int n = 0; n < 4; n++) {
        int col = n0 + wc * 64 + n * 16 + lr;
        float bv = bias ? bias[col] : 0.f;
#pragma unroll
        for (int m = 0; m < 4; m++) {
            int row = m0 + wr * 64 + m * 16 + rbase;
#pragma unroll
            for (int r = 0; r < 4; r++) {
                float val = acc[m][n][r] + bv;
                C[(size_t)(row + r) * N + col] = val;
                if (Cb) Cb[(size_t)(row + r) * N + col] = __float2bfloat16(val);
            }
        }
    }
}

// ---------------------------------------------------------------------------
// Low-rank gate, stage 1: xg[t, j] = h[t, :] @ Wgk1[:, j]   (j < 16)
// ---------------------------------------------------------------------------
__global__ __launch_bounds__(256) void lowrank1_kernel(const float* __restrict__ h,
                                                       const float* __restrict__ W1,
                                                       float* __restrict__ xg) {
    int idx = blockIdx.x * 256 + threadIdx.x;   // TT*16
    int t = idx >> 4, j = idx & 15;
    const float* hr = h + (size_t)t * DD;
    float s = 0.f;
    for (int kk = 0; kk < DD; kk++) s = fmaf(hr[kk], W1[kk * 16 + j], s);
    xg[idx] = s;
}

// ---------------------------------------------------------------------------
// Fused gate pipeline: per (chunk c, col): iterate 64 timesteps:
//   s = xg@W2col + bg; G += log_sigmoid(s)/16 (inclusive)
//   qhB = bf16(q*exp(G)*scale); khB = bf16(k*exp(-G))
// then Gl = G; ktT[c][h][dk][t'] = bf16(kh*exp(Gl)).
// grid: NCH*KDIM/256 = 64 blocks.
// ---------------------------------------------------------------------------
__global__ __launch_bounds__(256) void gatefuse_kernel(const float* __restrict__ qkvg,
                                                       const float* __restrict__ xg,
                                                       const float* __restrict__ W2,
                                                       const float* __restrict__ bg,
                                                       float* __restrict__ Gl,
                                                       __hip_bfloat16* __restrict__ qhB,
                                                       __hip_bfloat16* __restrict__ khB,
                                                       __hip_bfloat16* __restrict__ ktT) {
    int idx = blockIdx.x * 256 + threadIdx.x;    // NCH*KDIM
    int c = idx >> 9, col = idx & 511;
    float w2r[16];
#pragma unroll
    for (int r = 0; r < 16; r++) w2r[r] = W2[r * KDIM + col];
    const float bgv = bg[col];
    float G = 0.f;
    float kh[64];
#pragma unroll
    for (int t = 0; t < 64; t++) {
        const float* xr = xg + (size_t)(c * 64 + t) * 16;
        float s = bgv;
#pragma unroll
        for (int r = 0; r < 16; r++) s = fmaf(xr[r], w2r[r], s);
        float ls = fminf(s, 0.f) - log1pf(expf(-fabsf(s)));
        G += ls * (1.f / 16.f);
        const float* qp = qkvg + (size_t)(c * 64 + t) * QSTR + col;
        float qv = qp[0], kv = qp[512];
        qhB[(size_t)(c * 64 + t) * KDIM + col] = __float2bfloat16(qv * expf(G) * SCALE_Q);
        float khv = kv * expf(-G);
        khB[(size_t)(c * 64 + t) * KDIM + col] = __float2bfloat16(khv);
        kh[t] = khv;
    }
    Gl[idx] = G;
    float eGl = expf(G);
    int hh = col >> 7, dk = col & 127;
    __hip_bfloat16* kp = ktT + ((size_t)(c * NH + hh) * DKH + dk) * CH;
#pragma unroll
    for (int t = 0; t < 64; t++) kp[t] = __float2bfloat16(kh[t] * eGl);
}

// ---------------------------------------------------------------------------
// v transpose to bf16: vT[c][h][dv][t'] = bf16(v[t0+t'][h*256+dv]).
// grid = NCH*NH*4 (64-dv tiles).
// ---------------------------------------------------------------------------
__global__ __launch_bounds__(256) void vtrans_kernel(const float* __restrict__ qkvg,
                                                     __hip_bfloat16* __restrict__ vT) {
    __shared__ float tle[64][65];
    int bid = blockIdx.x;
    int dvq = bid & 3, hh = (bid >> 2) & 3, c = bid >> 4;
    int tid = threadIdx.x, ty = tid >> 4, tx = tid & 15;
#pragma unroll
    for (int u = 0; u < 4; u++) {
        int r = u * 16 + ty;   // t'
        float4 v = *(const float4*)(qkvg + (size_t)(c * 64 + r) * QSTR + 1024 + hh * DVH + dvq * 64 + tx * 4);
        tle[r][tx * 4 + 0] = v.x; tle[r][tx * 4 + 1] = v.y;
        tle[r][tx * 4 + 2] = v.z; tle[r][tx * 4 + 3] = v.w;
    }
    __syncthreads();
    __hip_bfloat16* dst = vT + ((size_t)(c * NH + hh) * DVH + dvq * 64) * CH;
#pragma unroll
    for (int u = 0; u < 4; u++) {
        int dv = u * 16 + ty;
        store_bf16x4(dst + (size_t)dv * CH + tx * 4,
                     tle[tx * 4 + 0][dv], tle[tx * 4 + 1][dv],
                     tle[tx * 4 + 2][dv], tle[tx * 4 + 3][dv]);
    }
}

// ---------------------------------------------------------------------------
// Chunk state contribution (transposed): U[c][h] (bf16 [256][128]) =
//   vT[c][h] ([256][64]) @ ktT[c][h]^T ([128][64] as Bt).  grid = NCH*NH, 4 waves.
// ---------------------------------------------------------------------------
__global__ __launch_bounds__(256) void chunkU_mfma(const __hip_bfloat16* __restrict__ vT,
                                                   const __hip_bfloat16* __restrict__ ktT,
                                                   __hip_bfloat16* __restrict__ U) {
    const int ch = blockIdx.x;
    const __hip_bfloat16* Ap = vT + (size_t)ch * DVH * CH;
    const __hip_bfloat16* Bp = ktT + (size_t)ch * DKH * CH;
    __hip_bfloat16* Cp = U + (size_t)ch * DVH * DKH;
    const int tid = threadIdx.x, wv = tid >> 6, lane = tid & 63;
    const int wr = wv >> 1, wc = wv & 1;
    const int lr = lane & 15, lk = (lane >> 4) * 8;
    f32x4 acc[8][4];
#pragma unroll
    for (int m = 0; m < 8; m++)
#pragma unroll
        for (int n = 0; n < 4; n++) acc[m][n] = (f32x4)(0.f);
#pragma unroll
    for (int ks = 0; ks < 2; ks++) {
        bf16x8 a[8], b[4];
#pragma unroll
        for (int m = 0; m < 8; m++)
            a[m] = *(const bf16x8*)(Ap + (size_t)(wr * 128 + m * 16 + lr) * CH + ks * 32 + lk);
#pragma unroll
        for (int n = 0; n < 4; n++)
            b[n] = *(const bf16x8*)(Bp + (size_t)(wc * 64 + n * 16 + lr) * CH + ks * 32 + lk);
#pragma unroll
        for (int m = 0; m < 8; m++)
#pragma unroll
            for (int n = 0; n < 4; n++)
                acc[m][n] = __builtin_amdgcn_mfma_f32_16x16x32_bf16(a[m], b[n], acc[m][n], 0, 0, 0);
    }
    const int r4 = (lane >> 4) * 4;
#pragma unroll
    for (int m = 0; m < 8; m++)
#pragma unroll
        for (int n = 0; n < 4; n++)
#pragma unroll
            for (int r = 0; r < 4; r++)
                Cp[(size_t)(wr * 128 + m * 16 + r4 + r) * DKH + wc * 64 + n * 16 + lr] =
                    __float2bfloat16(acc[m][n][r]);
}

// ---------------------------------------------------------------------------
// State recurrence over chunks, in place on bf16 U (contrib -> state-before).
// ---------------------------------------------------------------------------
__global__ __launch_bounds__(256) void scan_states_kernel(__hip_bfloat16* __restrict__ U,
                                                          const float* __restrict__ Gl) {
    int idx = blockIdx.x * 256 + threadIdx.x;   // NH*DVH*DKH = 131072
    int hh = idx >> 15, dv = (idx >> 7) & 255, dk = idx & 127;
    int col = hh * DKH + dk;
    float s = 0.f;
    for (int c = 0; c < NCH; c++) {
        __hip_bfloat16* p = U + ((size_t)(c * NH + hh) * DVH + dv) * DKH + dk;
        float u = __bfloat162float(*p);
        *p = __float2bfloat16(s);
        s = s * expf(Gl[c * KDIM + col]) + u;
    }
}

// ---------------------------------------------------------------------------
// MFMA attention: per (c, h, dv-half): S = Q̂K̂^T (f32, mask) -> P bf16 (LDS) ->
// O = P@V + Q̂@Sb^T.  grid = NCH*NH*2, 4 waves (wave = 16 q-rows).
// ---------------------------------------------------------------------------
__global__ __launch_bounds__(256) void attn_mfma(const __hip_bfloat16* __restrict__ qhB,
                                                 const __hip_bfloat16* __restrict__ khB,
                                                 const __hip_bfloat16* __restrict__ vT,
                                                 const __hip_bfloat16* __restrict__ Ub,
                                                 float* __restrict__ ob) {
    __shared__ __hip_bfloat16 P[64 * 72];
    const int bid = blockIdx.x;
    const int half = bid & 1, hh = (bid >> 1) & 3, c = bid >> 3;
    const int t0 = c * CH;
    const int tid = threadIdx.x, wv = tid >> 6, lane = tid & 63;
    const int lr = lane & 15, lk = (lane >> 4) * 8;
    const int r4 = (lane >> 4) * 4;

    // Q̂ A-fragments (rows wv*16+lr), kept in registers for S and O2
    bf16x8 qf[4];
#pragma unroll
    for (int ks = 0; ks < 4; ks++)
        qf[ks] = *(const bf16x8*)(qhB + (size_t)(t0 + wv * 16 + lr) * KDIM + hh * DKH + ks * 32 + lk);

    // S = Q̂ K̂^T  (wave rows x 64 cols)
    f32x4 s[4];
#pragma unroll
    for (int n = 0; n < 4; n++) s[n] = (f32x4)(0.f);
#pragma unroll
    for (int n = 0; n < 4; n++)
#pragma unroll
        for (int ks = 0; ks < 4; ks++) {
            bf16x8 kf = *(const bf16x8*)(khB + (size_t)(t0 + n * 16 + lr) * KDIM + hh * DKH + ks * 32 + lk);
            s[n] = __builtin_amdgcn_mfma_f32_16x16x32_bf16(qf[ks], kf, s[n], 0, 0, 0);
        }
    // causal mask, convert, stash in LDS (row stride 72 -> conflict-light)
#pragma unroll
    for (int n = 0; n < 4; n++)
#pragma unroll
        for (int r = 0; r < 4; r++) {
            int i = wv * 16 + r4 + r, j = n * 16 + lr;
            float val = (j <= i) ? s[n][r] : 0.f;
            P[i * 72 + j] = __float2bfloat16(val);
        }
    __syncthreads();

    // O = P@V + Q̂@Sb^T  over this block's 128-dv half
    const __hip_bfloat16* vTp = vT + ((size_t)(c * NH + hh) * DVH + half * 128) * CH;
    const __hip_bfloat16* Ubp = Ub + ((size_t)(c * NH + hh) * DVH + half * 128) * DKH;
    bf16x8 pf[2];
#pragma unroll
    for (int ks = 0; ks < 2; ks++)
        pf[ks] = *(const bf16x8*)&P[(wv * 16 + lr) * 72 + ks * 32 + lk];

    f32x4 o[8];
#pragma unroll
    for (int n = 0; n < 8; n++) o[n] = (f32x4)(0.f);
#pragma unroll
    for (int n = 0; n < 8; n++) {
#pragma unroll
        for (int ks = 0; ks < 2; ks++) {
            bf16x8 vf = *(const bf16x8*)(vTp + (size_t)(n * 16 + lr) * CH + ks * 32 + lk);
            o[n] = __builtin_amdgcn_mfma_f32_16x16x32_bf16(pf[ks], vf, o[n], 0, 0, 0);
        }
#pragma unroll
        for (int ks = 0; ks < 4; ks++) {
            bf16x8 uf = *(const bf16x8*)(Ubp + (size_t)(n * 16 + lr) * DKH + ks * 32 + lk);
            o[n] = __builtin_amdgcn_mfma_f32_16x16x32_bf16(qf[ks], uf, o[n], 0, 0, 0);
        }
    }
#pragma unroll
    for (int n = 0; n < 8; n++)
#pragma unroll
        for (int r = 0; r < 4; r++)
            ob[(size_t)(t0 + wv * 16 + r4 + r) * VDIM + hh * DVH + half * 128 + n * 16 + lr] = o[n][r];
}

// ---------------------------------------------------------------------------
// Per-(t,head) RMSNorm * gnw * swish(g) -> bf16
// ---------------------------------------------------------------------------
__global__ __launch_bounds__(256) void rms_swish_kernel(const float* __restrict__ o,
                                                        const float* __restrict__ qkvg,
                                                        const float* __restrict__ nw,
                                                        __hip_bfloat16* __restrict__ ob16) {
    int t = blockIdx.x;
    int tid = threadIdx.x;
    int wv = tid >> 6, ln = tid & 63;
    size_t base = (size_t)t * VDIM + wv * DVH + ln * 4;
    float4 x = *(const float4*)(o + base);
    float ss = x.x * x.x + x.y * x.y + x.z * x.z + x.w * x.w;
#pragma unroll
    for (int off = 32; off > 0; off >>= 1) ss += __shfl_xor(ss, off);
    float r = rsqrtf(ss * (1.f / 256.f) + 1e-5f);
    float4 gv = *(const float4*)(qkvg + (size_t)t * QSTR + 2048 + wv * DVH + ln * 4);
    float4 nv = *(const float4*)(nw + ln * 4);
    float a = x.x * r * nv.x * (gv.x / (1.f + expf(-gv.x)));
    float b = x.y * r * nv.y * (gv.y / (1.f + expf(-gv.y)));
    float c = x.z * r * nv.z * (gv.z / (1.f + expf(-gv.z)));
    float d = x.w * r * nv.w * (gv.w / (1.f + expf(-gv.w)));
    store_bf16x4(ob16 + base, a, b, c, d);
}

// ---------------------------------------------------------------------------
// Final LayerNorm over D=1024 per row -> bf16
// ---------------------------------------------------------------------------
__global__ __launch_bounds__(256) void ln_kernel(const float* __restrict__ h,
                                                 const float* __restrict__ w,
                                                 const float* __restrict__ b,
                                                 __hip_bfloat16* __restrict__ out16) {
    int t = blockIdx.x;
    int tid = threadIdx.x;
    float4 x = *(const float4*)(h + (size_t)t * DD + tid * 4);
    float s = x.x + x.y + x.z + x.w;
    float ss = x.x * x.x + x.y * x.y + x.z * x.z + x.w * x.w;
#pragma unroll
    for (int off = 32; off > 0; off >>= 1) {
        s += __shfl_xor(s, off);
        ss += __shfl_xor(ss, off);
    }
    __shared__ float rs[4], rss[4];
    int wv = tid >> 6;
    if ((tid & 63) == 0) { rs[wv] = s; rss[wv] = ss; }
    __syncthreads();
    s = rs[0] + rs[1] + rs[2] + rs[3];
    ss = rss[0] + rss[1] + rss[2] + rss[3];
    float mu = s * (1.f / 1024.f);
    float var = ss * (1.f / 1024.f) - mu * mu;
    float r = rsqrtf(var + 1e-5f);
    float4 wv4 = *(const float4*)(w + tid * 4);
    float4 bv4 = *(const float4*)(b + tid * 4);
    store_bf16x4(out16 + (size_t)t * DD + tid * 4,
                 (x.x - mu) * r * wv4.x + bv4.x,
                 (x.y - mu) * r * wv4.y + bv4.y,
                 (x.z - mu) * r * wv4.z + bv4.z,
                 (x.w - mu) * r * wv4.w + bv4.w);
}

// ---------------------------------------------------------------------------
extern "C" void kernel_launch(void* const* d_in, const int* in_sizes, int n_in,
                              void* d_out, int out_size, void* d_ws, size_t ws_size,
                              hipStream_t stream) {
    const int*   ids  = (const int*)d_in[0];
    const float* emb  = (const float*)d_in[1];
    const float* Wq   = (const float*)d_in[2];
    const float* Wk   = (const float*)d_in[3];
    const float* Wv   = (const float*)d_in[4];
    const float* Wg   = (const float*)d_in[5];
    const float* Wgk1 = (const float*)d_in[6];
    const float* Wgk2 = (const float*)d_in[7];
    const float* bgk  = (const float*)d_in[8];
    const float* gnw  = (const float*)d_in[9];
    const float* Wo   = (const float*)d_in[10];
    const float* lnw  = (const float*)d_in[11];
    const float* lnb  = (const float*)d_in[12];
    const float* Wlm  = (const float*)d_in[13];
    const float* blm  = (const float*)d_in[14];
    float* out = (float*)d_out;

    float* ws = (float*)d_ws;
    float* h    = ws; ws += (size_t)TT * DD;        // 8MB
    float* qkvg = ws; ws += (size_t)TT * QSTR;      // 25MB
    float* ob   = ws; ws += (size_t)TT * VDIM;      // 8MB
    float* xg   = ws; ws += (size_t)TT * 16;
    float* Gl   = ws; ws += (size_t)NCH * KDIM;
    __hip_bfloat16* hb    = (__hip_bfloat16*)ws; ws += (size_t)TT * DD / 2;     // 4MB
    __hip_bfloat16* obb   = (__hip_bfloat16*)ws; ws += (size_t)TT * DD / 2;
    __hip_bfloat16* lnb16 = (__hip_bfloat16*)ws; ws += (size_t)TT * DD / 2;
    __hip_bfloat16* qhB   = (__hip_bfloat16*)ws; ws += (size_t)TT * KDIM / 2;   // 2MB
    __hip_bfloat16* khB   = (__hip_bfloat16*)ws; ws += (size_t)TT * KDIM / 2;
    __hip_bfloat16* ktT   = (__hip_bfloat16*)ws; ws += (size_t)NCH * NH * DKH * CH / 2;  // 2MB
    __hip_bfloat16* vT    = (__hip_bfloat16*)ws; ws += (size_t)NCH * NH * DVH * CH / 2;  // 2MB
    __hip_bfloat16* Ub    = (__hip_bfloat16*)ws; ws += (size_t)NCH * NH * DVH * DKH / 2; // 8MB
    __hip_bfloat16* Wt    = (__hip_bfloat16*)ws; ws += (size_t)QSTR * DD / 2;   // 6MB
    __hip_bfloat16* WoT   = (__hip_bfloat16*)ws; ws += (size_t)VDIM * DD / 2;   // 2MB
    __hip_bfloat16* WlmT  = (__hip_bfloat16*)ws; ws += (size_t)VOCAB * DD / 2;  // 62.5MB

    embed_kernel<<<TT, 256, 0, stream>>>(ids, emb, h, hb);
    tconv_kernel<<<dim3(VOCAB / 64, DD / 64), 256, 0, stream>>>(Wlm, WlmT, DD, VOCAB);

    for (int l = 0; l < NL; l++) {
        const float* w1 = Wgk1 + (size_t)l * DD * 16;
        const float* w2 = Wgk2 + (size_t)l * 16 * KDIM;
        const float* bg = bgk + (size_t)l * KDIM;
        const float* nw = gnw + (size_t)l * DVH;

        tconv_layer_kernel<<<1024, 256, 0, stream>>>(Wq + (size_t)l * DD * KDIM,
                                                     Wk + (size_t)l * DD * KDIM,
                                                     Wv + (size_t)l * DD * VDIM,
                                                     Wg + (size_t)l * DD * VDIM,
                                                     Wo + (size_t)l * VDIM * DD, Wt, WoT);
        gemm_bf16_db<<<dim3(TT / 128, QSTR / 128), 256, 0, stream>>>(hb, Wt, nullptr, qkvg, nullptr, TT, QSTR, DD);
        lowrank1_kernel<<<TT * 16 / 256, 256, 0, stream>>>(h, w1, xg);
        gatefuse_kernel<<<NCH * KDIM / 256, 256, 0, stream>>>(qkvg, xg, w2, bg, Gl, qhB, khB, ktT);
        vtrans_kernel<<<NCH * NH * 4, 256, 0, stream>>>(qkvg, vT);
        chunkU_mfma<<<NCH * NH, 256, 0, stream>>>(vT, ktT, Ub);
        scan_states_kernel<<<NH * DVH * DKH / 256, 256, 0, stream>>>(Ub, Gl);
        attn_mfma<<<NCH * NH * 2, 256, 0, stream>>>(qhB, khB, vT, Ub, ob);
        rms_swish_kernel<<<TT, 256, 0, stream>>>(ob, qkvg, nw, obb);
        gemm_bf16_db<<<dim3(TT / 128, DD / 128), 256, 0, stream>>>(obb, WoT, nullptr, h, hb, TT, DD, VDIM);
    }

    ln_kernel<<<TT, 256, 0, stream>>>(h, lnw, lnb, lnb16);
    gemm_bf16_db<<<dim3(TT / 128, VOCAB / 128), 256, 0, stream>>>(lnb16, WlmT, blm, out, nullptr, TT, VOCAB, DD);
}

// Round 4
// 836.185 us; speedup vs baseline: 4.7814x; 1.1572x over previous
//
#include <hip/hip_runtime.h>
#include <hip/hip_bf16.h>
#include <math.h>

#define NL 4
#define TT 2048
#define DD 1024
#define KDIM 512
#define VDIM 1024
#define QSTR 3072     // fused qkvg row stride: q[0:512) k[512:1024) v[1024:2048) g[2048:3072)
#define NH 4
#define DKH 128
#define DVH 256
#define CH 64
#define NCH 32
#define VOCAB 32000
#define SCALE_Q 0.08838834764831845f

typedef short bf16x8 __attribute__((ext_vector_type(8)));
typedef float f32x4 __attribute__((ext_vector_type(4)));

__device__ __forceinline__ void gload_lds16(const void* g, void* l) {
    __builtin_amdgcn_global_load_lds((const __attribute__((address_space(1))) void*)g,
                                     (__attribute__((address_space(3))) void*)l, 16, 0, 0);
}

__device__ __forceinline__ void store_bf16x4(__hip_bfloat16* p, float a, float b, float c, float d) {
    union { __hip_bfloat16 h[4]; ushort4 v; } r;
    r.h[0] = __float2bfloat16(a); r.h[1] = __float2bfloat16(b);
    r.h[2] = __float2bfloat16(c); r.h[3] = __float2bfloat16(d);
    *(ushort4*)p = r.v;
}

// ---------------------------------------------------------------------------
// Embedding gather: h[t,:] = emb[ids[t],:] (f32 + bf16 copies)
// ---------------------------------------------------------------------------
__global__ __launch_bounds__(256) void embed_kernel(const int* __restrict__ ids,
                                                    const float* __restrict__ emb,
                                                    float* __restrict__ h,
                                                    __hip_bfloat16* __restrict__ hb) {
    int idx = blockIdx.x * 256 + threadIdx.x;      // TT*DD/4
    int t = idx >> 8, c4 = idx & 255;
    float4 v = *(const float4*)(emb + (size_t)ids[t] * DD + c4 * 4);
    *(float4*)(h + (size_t)t * DD + c4 * 4) = v;
    store_bf16x4(hb + (size_t)t * DD + c4 * 4, v.x, v.y, v.z, v.w);
}

// ---------------------------------------------------------------------------
// Transpose + convert: out[n][k] = bf16(in[k][n]).  in f32 [K][N]. grid (N/64, K/64)
// ---------------------------------------------------------------------------
__global__ __launch_bounds__(256) void tconv_kernel(const float* __restrict__ in,
                                                    __hip_bfloat16* __restrict__ out,
                                                    int K, int N) {
    __shared__ float tle[64][65];
    const int n0 = blockIdx.x * 64, k0 = blockIdx.y * 64;
    const int tid = threadIdx.x;
    const int ty = tid >> 4, tx = tid & 15;
#pragma unroll
    for (int u = 0; u < 4; u++) {
        int r = ty + u * 16;
        float4 v = *(const float4*)(in + (size_t)(k0 + r) * N + n0 + tx * 4);
        tle[r][tx * 4 + 0] = v.x; tle[r][tx * 4 + 1] = v.y;
        tle[r][tx * 4 + 2] = v.z; tle[r][tx * 4 + 3] = v.w;
    }
    __syncthreads();
#pragma unroll
    for (int u = 0; u < 4; u++) {
        int nn = u * 16 + ty;
        store_bf16x4(out + (size_t)(n0 + nn) * K + k0 + tx * 4,
                     tle[tx * 4 + 0][nn], tle[tx * 4 + 1][nn],
                     tle[tx * 4 + 2][nn], tle[tx * 4 + 3][nn]);
    }
}

// ---------------------------------------------------------------------------
// Per-layer weight transposes fused into one launch (1024 blocks).
// ---------------------------------------------------------------------------
__global__ __launch_bounds__(256) void tconv_layer_kernel(const float* __restrict__ wq,
                                                          const float* __restrict__ wk,
                                                          const float* __restrict__ wv,
                                                          const float* __restrict__ wg,
                                                          const float* __restrict__ wo,
                                                          __hip_bfloat16* __restrict__ Wt,
                                                          __hip_bfloat16* __restrict__ WoT) {
    __shared__ float tle[64][65];
    int b = blockIdx.x;
    const float* src; __hip_bfloat16* dst; int N, local;
    if (b < 128)      { src = wq; dst = Wt;                         N = 512;  local = b; }
    else if (b < 256) { src = wk; dst = Wt + (size_t)512 * 1024;    N = 512;  local = b - 128; }
    else if (b < 512) { src = wv; dst = Wt + (size_t)1024 * 1024;   N = 1024; local = b - 256; }
    else if (b < 768) { src = wg; dst = Wt + (size_t)2048 * 1024;   N = 1024; local = b - 512; }
    else              { src = wo; dst = WoT;                        N = 1024; local = b - 768; }
    int nbx = N >> 6;
    int n0 = (local % nbx) * 64, k0 = (local / nbx) * 64;
    const int tid = threadIdx.x;
    const int ty = tid >> 4, tx = tid & 15;
#pragma unroll
    for (int u = 0; u < 4; u++) {
        int r = ty + u * 16;
        float4 v = *(const float4*)(src + (size_t)(k0 + r) * N + n0 + tx * 4);
        tle[r][tx * 4 + 0] = v.x; tle[r][tx * 4 + 1] = v.y;
        tle[r][tx * 4 + 2] = v.z; tle[r][tx * 4 + 3] = v.w;
    }
    __syncthreads();
#pragma unroll
    for (int u = 0; u < 4; u++) {
        int nn = u * 16 + ty;
        store_bf16x4(dst + (size_t)(n0 + nn) * 1024 + k0 + tx * 4,
                     tle[tx * 4 + 0][nn], tle[tx * 4 + 1][nn],
                     tle[tx * 4 + 2][nn], tle[tx * 4 + 3][nn]);
    }
}

// ---------------------------------------------------------------------------
// bf16 MFMA GEMM, double-buffered 2-phase: C[M,N](f32) = A[M,K] @ Bt[N,K]^T (+bias).
// 128x128 tile, BK=32, 4 waves. XCD-swizzled grid (requires nwg % 8 == 0).
// Used for mid-size GEMMs (qkvg / Wo) where 256^2 tiles would underfill the grid.
// ---------------------------------------------------------------------------
__global__ __launch_bounds__(256) void gemm_bf16_db(const __hip_bfloat16* __restrict__ A,
                                                    const __hip_bfloat16* __restrict__ Bt,
                                                    const float* __restrict__ bias,
                                                    float* __restrict__ C,
                                                    __hip_bfloat16* __restrict__ Cb,
                                                    int M, int N, int K) {
    __shared__ short a_lds[2][128 * 32];
    __shared__ short b_lds[2][128 * 32];
    const int tid = threadIdx.x;
    const int wv = tid >> 6, lane = tid & 63;
    const int wr = wv >> 1, wc = wv & 1;
    const int nbx = gridDim.x;
    int wg = blockIdx.y * nbx + blockIdx.x;
    int cpx = (nbx * gridDim.y) >> 3;
    int swz = (wg & 7) * cpx + (wg >> 3);
    const int m0 = (swz % nbx) * 128, n0 = (swz / nbx) * 128;
    const int lr = lane & 15, lk = (lane >> 4) * 8;

    f32x4 acc[4][4];
#pragma unroll
    for (int m = 0; m < 4; m++)
#pragma unroll
        for (int n = 0; n < 4; n++) acc[m][n] = (f32x4)(0.f);

    auto STAGE = [&](int buf, int k0) {
#pragma unroll
        for (int u = 0; u < 2; u++) {
            int c = wv * 128 + u * 64 + lane;
            int r = c >> 2, kc = (c & 3) * 8;
            gload_lds16(A + (size_t)(m0 + r) * K + k0 + kc,
                        &a_lds[buf][(wv * 128 + u * 64) * 8]);
            gload_lds16(Bt + (size_t)(n0 + r) * K + k0 + kc,
                        &b_lds[buf][(wv * 128 + u * 64) * 8]);
        }
    };
    auto COMPUTE = [&](int buf) {
        bf16x8 af[4], bfr[4];
#pragma unroll
        for (int m = 0; m < 4; m++)
            af[m] = *(const bf16x8*)&a_lds[buf][(wr * 64 + m * 16 + lr) * 32 + lk];
#pragma unroll
        for (int n = 0; n < 4; n++)
            bfr[n] = *(const bf16x8*)&b_lds[buf][(wc * 64 + n * 16 + lr) * 32 + lk];
#pragma unroll
        for (int m = 0; m < 4; m++)
#pragma unroll
            for (int n = 0; n < 4; n++)
                acc[m][n] = __builtin_amdgcn_mfma_f32_16x16x32_bf16(af[m], bfr[n], acc[m][n], 0, 0, 0);
    };

    STAGE(0, 0);
    __syncthreads();
    int cur = 0;
    for (int k0 = 32; k0 < K; k0 += 32) {
        STAGE(cur ^ 1, k0);
        COMPUTE(cur);
        __syncthreads();
        cur ^= 1;
    }
    COMPUTE(cur);

    const int rbase = (lane >> 4) * 4;
#pragma unroll
    for (int n = 0; n < 4; n++) {
        int col = n0 + wc * 64 + n * 16 + lr;
        float bv = bias ? bias[col] : 0.f;
#pragma unroll
        for (int m = 0; m < 4; m++) {
            int row = m0 + wr * 64 + m * 16 + rbase;
#pragma unroll
            for (int r = 0; r < 4; r++) {
                float val = acc[m][n][r] + bv;
                C[(size_t)(row + r) * N + col] = val;
                if (Cb) Cb[(size_t)(row + r) * N + col] = __float2bfloat16(val);
            }
        }
    }
}

// ---------------------------------------------------------------------------
// 256x256 deep-pipelined MFMA GEMM (LM head). 512 thr = 8 waves (2Mx4N),
// per-wave C = 128x64. BK=32. 3 A-bufs + 5 B-bufs (16KB each) in 128KB dynamic
// LDS; prefetch distance A=2 / B=4 tiles; counted vmcnt(4) once per tile;
// setprio around MFMA clusters; XOR bank swizzle (inverse applied on the
// global source because global_load_lds writes linearly).
// LDS tile layout: logical byte of (row, cbyte) = (row>>1)*128 + (row&1)*64 + cbyte,
// physical = logical ^ (((logical>>7)&7)<<4).
// ---------------------------------------------------------------------------
__global__ __launch_bounds__(512, 1) void gemm256_lm(const __hip_bfloat16* __restrict__ A,
                                                     const __hip_bfloat16* __restrict__ Bt,
                                                     const float* __restrict__ bias,
                                                     float* __restrict__ C,
                                                     int M, int N, int K) {
    extern __shared__ __align__(16) char smem[];
    char* aB = smem;              // 3 x 16KB
    char* bB = smem + 3 * 16384;  // 5 x 16KB
    const int tid = threadIdx.x;
    const int wv = tid >> 6, lane = tid & 63;
    const int wr = wv >> 2, wc = wv & 3;
    const int lr = lane & 15, lk2 = ((lane >> 4) * 8) * 2;   // k-byte offset

    const int nbx = gridDim.x;
    int wg = blockIdx.y * nbx + blockIdx.x;
    int cpx = (nbx * gridDim.y) >> 3;
    int swz = (wg & 7) * cpx + (wg >> 3);
    const int m0 = (swz % nbx) * 256;
    const int n0 = (swz / nbx) * 256;

    // stage one 16KB tile (256 rows x 32 k bf16) of src panel row0, k-tile kt
    auto STAGE = [&](const __hip_bfloat16* src, int row0, char* dst, int kt) {
#pragma unroll
        for (int i = 0; i < 2; i++) {
            int o = (wv * 2 + i) * 1024;               // wave-uniform LDS chunk
            int ob = o + lane * 16;                    // this lane's linear slot
            int lg = ob ^ (((ob >> 7) & 7) << 4);      // logical byte it must hold
            int row = lg >> 6;
            int ce = (lg & 63) >> 1;                   // k element within tile
            gload_lds16(src + (size_t)(row0 + row) * K + kt * 32 + ce, dst + o);
        }
    };
    auto FRAG = [&](const char* buf, int row) -> bf16x8 {
        int lg = ((row >> 1) << 7) + ((row & 1) << 6) + lk2;
        return *(const bf16x8*)(buf + (lg ^ (((row >> 1) & 7) << 4)));
    };

    f32x4 acc[8][4];
#pragma unroll
    for (int m = 0; m < 8; m++)
#pragma unroll
        for (int n = 0; n < 4; n++) acc[m][n] = (f32x4)(0.f);

    const int NT = K / 32;
    // prologue: A tiles 0,1 ; B tiles 0..3
    STAGE(A,  m0, aB + 0 * 16384, 0);
    STAGE(A,  m0, aB + 1 * 16384, 1);
    STAGE(Bt, n0, bB + 0 * 16384, 0);
    STAGE(Bt, n0, bB + 1 * 16384, 1);
    STAGE(Bt, n0, bB + 2 * 16384, 2);
    STAGE(Bt, n0, bB + 3 * 16384, 3);
    asm volatile("s_waitcnt vmcnt(0)" ::: "memory");
    __builtin_amdgcn_s_barrier();

    for (int t = 0; t < NT; t++) {
        const char* ab = aB + (t % 3) * 16384;
        const char* bb = bB + (t % 5) * 16384;
        bf16x8 bfr[4], af[4];
        // ---- phase 0: B frags + A rows 0-63 of wave range ----
#pragma unroll
        for (int n = 0; n < 4; n++) bfr[n] = FRAG(bb, wc * 64 + n * 16 + lr);
#pragma unroll
        for (int m = 0; m < 4; m++) af[m] = FRAG(ab, wr * 128 + m * 16 + lr);
        { int ta = t + 2 < NT ? t + 2 : NT - 1;          // clamp keeps vmcnt exact
          STAGE(A, m0, aB + ((t + 2) % 3) * 16384, ta); }
        __builtin_amdgcn_sched_barrier(0);
        __builtin_amdgcn_s_barrier();
        __builtin_amdgcn_sched_barrier(0);
        __builtin_amdgcn_s_setprio(1);
#pragma unroll
        for (int m = 0; m < 4; m++)
#pragma unroll
            for (int n = 0; n < 4; n++)
                acc[m][n] = __builtin_amdgcn_mfma_f32_16x16x32_bf16(af[m], bfr[n], acc[m][n], 0, 0, 0);
        __builtin_amdgcn_s_setprio(0);
        __builtin_amdgcn_sched_barrier(0);
        __builtin_amdgcn_s_barrier();
        // ---- phase 1: A rows 64-127 of wave range ----
#pragma unroll
        for (int m = 0; m < 4; m++) af[m] = FRAG(ab, wr * 128 + (m + 4) * 16 + lr);
        { int tb = t + 4 < NT ? t + 4 : NT - 1;
          STAGE(Bt, n0, bB + ((t + 4) % 5) * 16384, tb); }
        __builtin_amdgcn_sched_barrier(0);
        __builtin_amdgcn_s_barrier();
        __builtin_amdgcn_sched_barrier(0);
        __builtin_amdgcn_s_setprio(1);
#pragma unroll
        for (int m = 0; m < 4; m++)
#pragma unroll
            for (int n = 0; n < 4; n++)
                acc[m + 4][n] = __builtin_amdgcn_mfma_f32_16x16x32_bf16(af[m], bfr[n], acc[m + 4][n], 0, 0, 0);
        __builtin_amdgcn_s_setprio(0);
        __builtin_amdgcn_sched_barrier(0);
        asm volatile("s_waitcnt vmcnt(4)" ::: "memory");  // allow only this iter's 4 loads in flight
        __builtin_amdgcn_s_barrier();
    }

    const int r4 = (lane >> 4) * 4;
#pragma unroll
    for (int n = 0; n < 4; n++) {
        int col = n0 + wc * 64 + n * 16 + lr;
        float bv = bias ? bias[col] : 0.f;
#pragma unroll
        for (int m = 0; m < 8; m++) {
            int row = m0 + wr * 128 + m * 16 + r4;
#pragma unroll
            for (int r = 0; r < 4; r++)
                C[(size_t)(row + r) * N + col] = acc[m][n][r] + bv;
        }
    }
}

// ---------------------------------------------------------------------------
// Low-rank gate, stage 1: xg[t, j] = h[t, :] @ Wgk1[:, j]   (j < 16)
// One block per row; 16 k-slices x 16 outputs; LDS reduce.
// ---------------------------------------------------------------------------
__global__ __launch_bounds__(256) void lowrank1_kernel(const float* __restrict__ h,
                                                       const float* __restrict__ W1,
                                                       float* __restrict__ xg) {
    int t = blockIdx.x;
    int tid = threadIdx.x;
    int j = tid & 15, ks = tid >> 4;
    const float* hr = h + (size_t)t * DD + ks * 64;
    const float* w = W1 + (size_t)(ks * 64) * 16 + j;
    float acc = 0.f;
#pragma unroll 8
    for (int kk = 0; kk < 64; kk++) acc = fmaf(hr[kk], w[kk * 16], acc);
    __shared__ float red[16][17];
    red[ks][j] = acc;
    __syncthreads();
    if (tid < 16) {
        float s = 0.f;
#pragma unroll
        for (int r = 0; r < 16; r++) s += red[r][tid];
        xg[t * 16 + tid] = s;
    }
}

// ---------------------------------------------------------------------------
// Fused gate pipeline: per (chunk c, col): iterate 64 timesteps:
//   s = xg@W2col + bg; G += log_sigmoid(s)/16 (inclusive)
//   qhB = bf16(q*exp(G)*scale); khB = bf16(k*exp(-G))
// then Gl = G; ktT[c][h][dk][t'] = bf16(kh*exp(Gl)).
// ---------------------------------------------------------------------------
__global__ __launch_bounds__(256) void gatefuse_kernel(const float* __restrict__ qkvg,
                                                       const float* __restrict__ xg,
                                                       const float* __restrict__ W2,
                                                       const float* __restrict__ bg,
                                                       float* __restrict__ Gl,
                                                       __hip_bfloat16* __restrict__ qhB,
                                                       __hip_bfloat16* __restrict__ khB,
                                                       __hip_bfloat16* __restrict__ ktT) {
    int idx = blockIdx.x * 256 + threadIdx.x;    // NCH*KDIM
    int c = idx >> 9, col = idx & 511;
    float w2r[16];
#pragma unroll
    for (int r = 0; r < 16; r++) w2r[r] = W2[r * KDIM + col];
    const float bgv = bg[col];
    float G = 0.f;
    float kh[64];
#pragma unroll
    for (int t = 0; t < 64; t++) {
        const float* xr = xg + (size_t)(c * 64 + t) * 16;
        float s = bgv;
#pragma unroll
        for (int r = 0; r < 16; r++) s = fmaf(xr[r], w2r[r], s);
        float ls = fminf(s, 0.f) - log1pf(expf(-fabsf(s)));
        G += ls * (1.f / 16.f);
        const float* qp = qkvg + (size_t)(c * 64 + t) * QSTR + col;
        float qv = qp[0], kv = qp[512];
        qhB[(size_t)(c * 64 + t) * KDIM + col] = __float2bfloat16(qv * expf(G) * SCALE_Q);
        float khv = kv * expf(-G);
        khB[(size_t)(c * 64 + t) * KDIM + col] = __float2bfloat16(khv);
        kh[t] = khv;
    }
    Gl[idx] = G;
    float eGl = expf(G);
    int hh = col >> 7, dk = col & 127;
    __hip_bfloat16* kp = ktT + ((size_t)(c * NH + hh) * DKH + dk) * CH;
#pragma unroll
    for (int t = 0; t < 64; t++) kp[t] = __float2bfloat16(kh[t] * eGl);
}

// ---------------------------------------------------------------------------
// v transpose to bf16: vT[c][h][dv][t'] = bf16(v[t0+t'][h*256+dv]).
// ---------------------------------------------------------------------------
__global__ __launch_bounds__(256) void vtrans_kernel(const float* __restrict__ qkvg,
                                                     __hip_bfloat16* __restrict__ vT) {
    __shared__ float tle[64][65];
    int bid = blockIdx.x;
    int dvq = bid & 3, hh = (bid >> 2) & 3, c = bid >> 4;
    int tid = threadIdx.x, ty = tid >> 4, tx = tid & 15;
#pragma unroll
    for (int u = 0; u < 4; u++) {
        int r = u * 16 + ty;   // t'
        float4 v = *(const float4*)(qkvg + (size_t)(c * 64 + r) * QSTR + 1024 + hh * DVH + dvq * 64 + tx * 4);
        tle[r][tx * 4 + 0] = v.x; tle[r][tx * 4 + 1] = v.y;
        tle[r][tx * 4 + 2] = v.z; tle[r][tx * 4 + 3] = v.w;
    }
    __syncthreads();
    __hip_bfloat16* dst = vT + ((size_t)(c * NH + hh) * DVH + dvq * 64) * CH;
#pragma unroll
    for (int u = 0; u < 4; u++) {
        int dv = u * 16 + ty;
        store_bf16x4(dst + (size_t)dv * CH + tx * 4,
                     tle[tx * 4 + 0][dv], tle[tx * 4 + 1][dv],
                     tle[tx * 4 + 2][dv], tle[tx * 4 + 3][dv]);
    }
}

// ---------------------------------------------------------------------------
// Chunk state contribution (transposed): U[c][h] (bf16 [256][128]) =
//   vT[c][h] ([256][64]) @ ktT[c][h]^T ([128][64] as Bt).  grid = NCH*NH, 4 waves.
// ---------------------------------------------------------------------------
__global__ __launch_bounds__(256) void chunkU_mfma(const __hip_bfloat16* __restrict__ vT,
                                                   const __hip_bfloat16* __restrict__ ktT,
                                                   __hip_bfloat16* __restrict__ U) {
    const int ch = blockIdx.x;
    const __hip_bfloat16* Ap = vT + (size_t)ch * DVH * CH;
    const __hip_bfloat16* Bp = ktT + (size_t)ch * DKH * CH;
    __hip_bfloat16* Cp = U + (size_t)ch * DVH * DKH;
    const int tid = threadIdx.x, wv = tid >> 6, lane = tid & 63;
    const int wr = wv >> 1, wc = wv & 1;
    const int lr = lane & 15, lk = (lane >> 4) * 8;
    f32x4 acc[8][4];
#pragma unroll
    for (int m = 0; m < 8; m++)
#pragma unroll
        for (int n = 0; n < 4; n++) acc[m][n] = (f32x4)(0.f);
#pragma unroll
    for (int ks = 0; ks < 2; ks++) {
        bf16x8 a[8], b[4];
#pragma unroll
        for (int m = 0; m < 8; m++)
            a[m] = *(const bf16x8*)(Ap + (size_t)(wr * 128 + m * 16 + lr) * CH + ks * 32 + lk);
#pragma unroll
        for (int n = 0; n < 4; n++)
            b[n] = *(const bf16x8*)(Bp + (size_t)(wc * 64 + n * 16 + lr) * CH + ks * 32 + lk);
#pragma unroll
        for (int m = 0; m < 8; m++)
#pragma unroll
            for (int n = 0; n < 4; n++)
                acc[m][n] = __builtin_amdgcn_mfma_f32_16x16x32_bf16(a[m], b[n], acc[m][n], 0, 0, 0);
    }
    const int r4 = (lane >> 4) * 4;
#pragma unroll
    for (int m = 0; m < 8; m++)
#pragma unroll
        for (int n = 0; n < 4; n++)
#pragma unroll
            for (int r = 0; r < 4; r++)
                Cp[(size_t)(wr * 128 + m * 16 + r4 + r) * DKH + wc * 64 + n * 16 + lr] =
                    __float2bfloat16(acc[m][n][r]);
}

// ---------------------------------------------------------------------------
// State recurrence over chunks, in place on bf16 U (contrib -> state-before).
// ---------------------------------------------------------------------------
__global__ __launch_bounds__(256) void scan_states_kernel(__hip_bfloat16* __restrict__ U,
                                                          const float* __restrict__ Gl) {
    int idx = blockIdx.x * 256 + threadIdx.x;   // NH*DVH*DKH = 131072
    int hh = idx >> 15, dv = (idx >> 7) & 255, dk = idx & 127;
    int col = hh * DKH + dk;
    float s = 0.f;
    for (int c = 0; c < NCH; c++) {
        __hip_bfloat16* p = U + ((size_t)(c * NH + hh) * DVH + dv) * DKH + dk;
        float u = __bfloat162float(*p);
        *p = __float2bfloat16(s);
        s = s * expf(Gl[c * KDIM + col]) + u;
    }
}

// ---------------------------------------------------------------------------
// MFMA attention: per (c, h, dv-half): S = Q̂K̂^T (f32, mask) -> P bf16 (LDS) ->
// O = P@V + Q̂@Sb^T.  grid = NCH*NH*2, 4 waves (wave = 16 q-rows).
// ---------------------------------------------------------------------------
__global__ __launch_bounds__(256) void attn_mfma(const __hip_bfloat16* __restrict__ qhB,
                                                 const __hip_bfloat16* __restrict__ khB,
                                                 const __hip_bfloat16* __restrict__ vT,
                                                 const __hip_bfloat16* __restrict__ Ub,
                                                 float* __restrict__ ob) {
    __shared__ __hip_bfloat16 P[64 * 72];
    const int bid = blockIdx.x;
    const int half = bid & 1, hh = (bid >> 1) & 3, c = bid >> 3;
    const int t0 = c * CH;
    const int tid = threadIdx.x, wv = tid >> 6, lane = tid & 63;
    const int lr = lane & 15, lk = (lane >> 4) * 8;
    const int r4 = (lane >> 4) * 4;

    bf16x8 qf[4];
#pragma unroll
    for (int ks = 0; ks < 4; ks++)
        qf[ks] = *(const bf16x8*)(qhB + (size_t)(t0 + wv * 16 + lr) * KDIM + hh * DKH + ks * 32 + lk);

    f32x4 s[4];
#pragma unroll
    for (int n = 0; n < 4; n++) s[n] = (f32x4)(0.f);
#pragma unroll
    for (int n = 0; n < 4; n++)
#pragma unroll
        for (int ks = 0; ks < 4; ks++) {
            bf16x8 kf = *(const bf16x8*)(khB + (size_t)(t0 + n * 16 + lr) * KDIM + hh * DKH + ks * 32 + lk);
            s[n] = __builtin_amdgcn_mfma_f32_16x16x32_bf16(qf[ks], kf, s[n], 0, 0, 0);
        }
#pragma unroll
    for (int n = 0; n < 4; n++)
#pragma unroll
        for (int r = 0; r < 4; r++) {
            int i = wv * 16 + r4 + r, j = n * 16 + lr;
            float val = (j <= i) ? s[n][r] : 0.f;
            P[i * 72 + j] = __float2bfloat16(val);
        }
    __syncthreads();

    const __hip_bfloat16* vTp = vT + ((size_t)(c * NH + hh) * DVH + half * 128) * CH;
    const __hip_bfloat16* Ubp = Ub + ((size_t)(c * NH + hh) * DVH + half * 128) * DKH;
    bf16x8 pf[2];
#pragma unroll
    for (int ks = 0; ks < 2; ks++)
        pf[ks] = *(const bf16x8*)&P[(wv * 16 + lr) * 72 + ks * 32 + lk];

    f32x4 o[8];
#pragma unroll
    for (int n = 0; n < 8; n++) o[n] = (f32x4)(0.f);
#pragma unroll
    for (int n = 0; n < 8; n++) {
#pragma unroll
        for (int ks = 0; ks < 2; ks++) {
            bf16x8 vf = *(const bf16x8*)(vTp + (size_t)(n * 16 + lr) * CH + ks * 32 + lk);
            o[n] = __builtin_amdgcn_mfma_f32_16x16x32_bf16(pf[ks], vf, o[n], 0, 0, 0);
        }
#pragma unroll
        for (int ks = 0; ks < 4; ks++) {
            bf16x8 uf = *(const bf16x8*)(Ubp + (size_t)(n * 16 + lr) * DKH + ks * 32 + lk);
            o[n] = __builtin_amdgcn_mfma_f32_16x16x32_bf16(qf[ks], uf, o[n], 0, 0, 0);
        }
    }
#pragma unroll
    for (int n = 0; n < 8; n++)
#pragma unroll
        for (int r = 0; r < 4; r++)
            ob[(size_t)(t0 + wv * 16 + r4 + r) * VDIM + hh * DVH + half * 128 + n * 16 + lr] = o[n][r];
}

// ---------------------------------------------------------------------------
// Per-(t,head) RMSNorm * gnw * swish(g) -> bf16
// ---------------------------------------------------------------------------
__global__ __launch_bounds__(256) void rms_swish_kernel(const float* __restrict__ o,
                                                        const float* __restrict__ qkvg,
                                                        const float* __restrict__ nw,
                                                        __hip_bfloat16* __restrict__ ob16) {
    int t = blockIdx.x;
    int tid = threadIdx.x;
    int wv = tid >> 6, ln = tid & 63;
    size_t base = (size_t)t * VDIM + wv * DVH + ln * 4;
    float4 x = *(const float4*)(o + base);
    float ss = x.x * x.x + x.y * x.y + x.z * x.z + x.w * x.w;
#pragma unroll
    for (int off = 32; off > 0; off >>= 1) ss += __shfl_xor(ss, off);
    float r = rsqrtf(ss * (1.f / 256.f) + 1e-5f);
    float4 gv = *(const float4*)(qkvg + (size_t)t * QSTR + 2048 + wv * DVH + ln * 4);
    float4 nv = *(const float4*)(nw + ln * 4);
    float a = x.x * r * nv.x * (gv.x / (1.f + expf(-gv.x)));
    float b = x.y * r * nv.y * (gv.y / (1.f + expf(-gv.y)));
    float c = x.z * r * nv.z * (gv.z / (1.f + expf(-gv.z)));
    float d = x.w * r * nv.w * (gv.w / (1.f + expf(-gv.w)));
    store_bf16x4(ob16 + base, a, b, c, d);
}

// ---------------------------------------------------------------------------
// Final LayerNorm over D=1024 per row -> bf16
// ---------------------------------------------------------------------------
__global__ __launch_bounds__(256) void ln_kernel(const float* __restrict__ h,
                                                 const float* __restrict__ w,
                                                 const float* __restrict__ b,
                                                 __hip_bfloat16* __restrict__ out16) {
    int t = blockIdx.x;
    int tid = threadIdx.x;
    float4 x = *(const float4*)(h + (size_t)t * DD + tid * 4);
    float s = x.x + x.y + x.z + x.w;
    float ss = x.x * x.x + x.y * x.y + x.z * x.z + x.w * x.w;
#pragma unroll
    for (int off = 32; off > 0; off >>= 1) {
        s += __shfl_xor(s, off);
        ss += __shfl_xor(ss, off);
    }
    __shared__ float rs[4], rss[4];
    int wv = tid >> 6;
    if ((tid & 63) == 0) { rs[wv] = s; rss[wv] = ss; }
    __syncthreads();
    s = rs[0] + rs[1] + rs[2] + rs[3];
    ss = rss[0] + rss[1] + rss[2] + rss[3];
    float mu = s * (1.f / 1024.f);
    float var = ss * (1.f / 1024.f) - mu * mu;
    float r = rsqrtf(var + 1e-5f);
    float4 wv4 = *(const float4*)(w + tid * 4);
    float4 bv4 = *(const float4*)(b + tid * 4);
    store_bf16x4(out16 + (size_t)t * DD + tid * 4,
                 (x.x - mu) * r * wv4.x + bv4.x,
                 (x.y - mu) * r * wv4.y + bv4.y,
                 (x.z - mu) * r * wv4.z + bv4.z,
                 (x.w - mu) * r * wv4.w + bv4.w);
}

// ---------------------------------------------------------------------------
extern "C" void kernel_launch(void* const* d_in, const int* in_sizes, int n_in,
                              void* d_out, int out_size, void* d_ws, size_t ws_size,
                              hipStream_t stream) {
    const int*   ids  = (const int*)d_in[0];
    const float* emb  = (const float*)d_in[1];
    const float* Wq   = (const float*)d_in[2];
    const float* Wk   = (const float*)d_in[3];
    const float* Wv   = (const float*)d_in[4];
    const float* Wg   = (const float*)d_in[5];
    const float* Wgk1 = (const float*)d_in[6];
    const float* Wgk2 = (const float*)d_in[7];
    const float* bgk  = (const float*)d_in[8];
    const float* gnw  = (const float*)d_in[9];
    const float* Wo   = (const float*)d_in[10];
    const float* lnw  = (const float*)d_in[11];
    const float* lnb  = (const float*)d_in[12];
    const float* Wlm  = (const float*)d_in[13];
    const float* blm  = (const float*)d_in[14];
    float* out = (float*)d_out;

    float* ws = (float*)d_ws;
    float* h    = ws; ws += (size_t)TT * DD;        // 8MB
    float* qkvg = ws; ws += (size_t)TT * QSTR;      // 25MB
    float* ob   = ws; ws += (size_t)TT * VDIM;      // 8MB
    float* xg   = ws; ws += (size_t)TT * 16;
    float* Gl   = ws; ws += (size_t)NCH * KDIM;
    __hip_bfloat16* hb    = (__hip_bfloat16*)ws; ws += (size_t)TT * DD / 2;     // 4MB
    __hip_bfloat16* obb   = (__hip_bfloat16*)ws; ws += (size_t)TT * DD / 2;
    __hip_bfloat16* lnb16 = (__hip_bfloat16*)ws; ws += (size_t)TT * DD / 2;
    __hip_bfloat16* qhB   = (__hip_bfloat16*)ws; ws += (size_t)TT * KDIM / 2;   // 2MB
    __hip_bfloat16* khB   = (__hip_bfloat16*)ws; ws += (size_t)TT * KDIM / 2;
    __hip_bfloat16* ktT   = (__hip_bfloat16*)ws; ws += (size_t)NCH * NH * DKH * CH / 2;  // 2MB
    __hip_bfloat16* vT    = (__hip_bfloat16*)ws; ws += (size_t)NCH * NH * DVH * CH / 2;  // 2MB
    __hip_bfloat16* Ub    = (__hip_bfloat16*)ws; ws += (size_t)NCH * NH * DVH * DKH / 2; // 8MB
    __hip_bfloat16* Wt    = (__hip_bfloat16*)ws; ws += (size_t)QSTR * DD / 2;   // 6MB
    __hip_bfloat16* WoT   = (__hip_bfloat16*)ws; ws += (size_t)VDIM * DD / 2;   // 2MB
    __hip_bfloat16* WlmT  = (__hip_bfloat16*)ws; ws += (size_t)VOCAB * DD / 2;  // 62.5MB

    hipFuncSetAttribute((const void*)gemm256_lm,
                        hipFuncAttributeMaxDynamicSharedMemorySize, 131072);

    embed_kernel<<<TT, 256, 0, stream>>>(ids, emb, h, hb);
    tconv_kernel<<<dim3(VOCAB / 64, DD / 64), 256, 0, stream>>>(Wlm, WlmT, DD, VOCAB);

    for (int l = 0; l < NL; l++) {
        const float* w1 = Wgk1 + (size_t)l * DD * 16;
        const float* w2 = Wgk2 + (size_t)l * 16 * KDIM;
        const float* bg = bgk + (size_t)l * KDIM;
        const float* nw = gnw + (size_t)l * DVH;

        tconv_layer_kernel<<<1024, 256, 0, stream>>>(Wq + (size_t)l * DD * KDIM,
                                                     Wk + (size_t)l * DD * KDIM,
                                                     Wv + (size_t)l * DD * VDIM,
                                                     Wg + (size_t)l * DD * VDIM,
                                                     Wo + (size_t)l * VDIM * DD, Wt, WoT);
        gemm_bf16_db<<<dim3(TT / 128, QSTR / 128), 256, 0, stream>>>(hb, Wt, nullptr, qkvg, nullptr, TT, QSTR, DD);
        lowrank1_kernel<<<TT, 256, 0, stream>>>(h, w1, xg);
        gatefuse_kernel<<<NCH * KDIM / 256, 256, 0, stream>>>(qkvg, xg, w2, bg, Gl, qhB, khB, ktT);
        vtrans_kernel<<<NCH * NH * 4, 256, 0, stream>>>(qkvg, vT);
        chunkU_mfma<<<NCH * NH, 256, 0, stream>>>(vT, ktT, Ub);
        scan_states_kernel<<<NH * DVH * DKH / 256, 256, 0, stream>>>(Ub, Gl);
        attn_mfma<<<NCH * NH * 2, 256, 0, stream>>>(qhB, khB, vT, Ub, ob);
        rms_swish_kernel<<<TT, 256, 0, stream>>>(ob, qkvg, nw, obb);
        gemm_bf16_db<<<dim3(TT / 128, DD / 128), 256, 0, stream>>>(obb, WoT, nullptr, h, hb, TT, DD, VDIM);
    }

    ln_kernel<<<TT, 256, 0, stream>>>(h, lnw, lnb, lnb16);
    gemm256_lm<<<dim3(TT / 256, VOCAB / 256), 512, 131072, stream>>>(lnb16, WlmT, blm, out, TT, VOCAB, DD);
}